// Round 1
// baseline (895.229 us; speedup 1.0000x reference)
//
#include <hip/hip_runtime.h>
#include <stdint.h>

#define Bdim 2
#define Tdim 2048
#define Cdim 2048
#define Hdim 16
#define HKVdim 4
#define Ddim 128
#define KVdim 512   // HKV*D

typedef __attribute__((ext_vector_type(8))) short bf16x8;
typedef __attribute__((ext_vector_type(4))) float f32x4;

__device__ __forceinline__ unsigned short f2bf(float f) {
  union { float f; unsigned u; } a; a.f = f;
  unsigned u = a.u + 0x7FFFu + ((a.u >> 16) & 1u);   // RNE
  return (unsigned short)(u >> 16);
}
__device__ __forceinline__ float bf2f(unsigned short h) {
  union { float f; unsigned u; } a; a.u = ((unsigned)h) << 16;
  return a.f;
}

// ---------------- split x into bf16 hi/lo ----------------
__global__ void split_x_kernel(const float* __restrict__ x, unsigned short* __restrict__ hi,
                               unsigned short* __restrict__ lo, int n) {
  int i = blockIdx.x * blockDim.x + threadIdx.x;
  int stride = gridDim.x * blockDim.x;
  for (; i < n; i += stride) {
    float f = x[i];
    unsigned short hb = f2bf(f);
    hi[i] = hb;
    lo[i] = f2bf(f - bf2f(hb));
  }
}

// ---------------- transpose (K,N) fp32 -> (N,K) bf16 hi (+lo) ----------------
__global__ void transpose_split_kernel(const float* __restrict__ in, unsigned short* __restrict__ hi,
                                       unsigned short* __restrict__ lo, int K, int N) {
  __shared__ float tile[32][33];
  int k0 = blockIdx.x * 32, n0 = blockIdx.y * 32;
  int tx = threadIdx.x, ty = threadIdx.y;
#pragma unroll
  for (int i = 0; i < 32; i += 8)
    tile[ty + i][tx] = in[(size_t)(k0 + ty + i) * N + n0 + tx];
  __syncthreads();
#pragma unroll
  for (int i = 0; i < 32; i += 8) {
    float f = tile[tx][ty + i];
    size_t o = (size_t)(n0 + ty + i) * K + k0 + tx;
    unsigned short hb = f2bf(f);
    hi[o] = hb;
    if (lo) lo[o] = f2bf(f - bf2f(hb));
  }
}

// ---------------- GEMM: C(M,N) (+)= A(M,K) @ Bt(N,K)^T, bf16 in fp32 out ----------------
// 128x128 tile, BK=32, 4 waves (2x2), 4x4 16x16x32 MFMA per wave, reg-staged LDS (stride 40)
__global__ __launch_bounds__(256) void gemm_bt_kernel(
    const unsigned short* __restrict__ A, const unsigned short* __restrict__ Bt,
    float* __restrict__ C, int M, int N, int K, int accumulate)
{
  __shared__ alignas(16) unsigned short sA[128 * 40];
  __shared__ alignas(16) unsigned short sB[128 * 40];
  int tid = threadIdx.x;
  int wid = tid >> 6, lane = tid & 63;
  int bm = blockIdx.x, bn = blockIdx.y;
  int wr = wid >> 1, wc = wid & 1;
  int ln15 = lane & 15, ko8 = (lane >> 4) * 8;

  f32x4 acc[4][4];
#pragma unroll
  for (int m = 0; m < 4; ++m)
#pragma unroll
    for (int n = 0; n < 4; ++n)
      acc[m][n] = f32x4{0.f, 0.f, 0.f, 0.f};

  int nk = K >> 5;
  for (int kt = 0; kt < nk; ++kt) {
    // stage A and B tiles: 512 chunks of 8 elems each, 2 per thread
#pragma unroll
    for (int it = 0; it < 2; ++it) {
      int c = it * 256 + tid;
      int row = c >> 2;
      int k8 = (c & 3) * 8;
      *(bf16x8*)&sA[row * 40 + k8] =
          *(const bf16x8*)(A + (size_t)(bm * 128 + row) * K + kt * 32 + k8);
      *(bf16x8*)&sB[row * 40 + k8] =
          *(const bf16x8*)(Bt + (size_t)(bn * 128 + row) * K + kt * 32 + k8);
    }
    __syncthreads();
    bf16x8 af[4], bfv[4];
#pragma unroll
    for (int m = 0; m < 4; ++m)
      af[m] = *(const bf16x8*)&sA[(wr * 64 + m * 16 + ln15) * 40 + ko8];
#pragma unroll
    for (int n = 0; n < 4; ++n)
      bfv[n] = *(const bf16x8*)&sB[(wc * 64 + n * 16 + ln15) * 40 + ko8];
#pragma unroll
    for (int m = 0; m < 4; ++m)
#pragma unroll
      for (int n = 0; n < 4; ++n)
        acc[m][n] = __builtin_amdgcn_mfma_f32_16x16x32_bf16(af[m], bfv[n], acc[m][n], 0, 0, 0);
    __syncthreads();
  }

  int orow0 = bm * 128 + wr * 64 + (lane >> 4) * 4;
  int ocol0 = bn * 128 + wc * 64 + ln15;
#pragma unroll
  for (int m = 0; m < 4; ++m)
#pragma unroll
    for (int n = 0; n < 4; ++n)
#pragma unroll
      for (int r = 0; r < 4; ++r) {
        size_t idx = (size_t)(orow0 + m * 16 + r) * N + ocol0 + n * 16;
        if (accumulate) C[idx] += acc[m][n][r];
        else C[idx] = acc[m][n][r];
      }
}

// ---------------- RoPE + reshape + split: (b*T, nh*128) fp32 -> (b,h,t,d) bf16 hi/lo ----------------
__global__ void rope_kernel(const float* __restrict__ src, const float* __restrict__ cs,
                            const float* __restrict__ sn, unsigned short* __restrict__ hi,
                            unsigned short* __restrict__ lo, int nh) {
  int row = blockIdx.x;           // b*T + t
  int h = blockIdx.y;
  int d = threadIdx.x;
  int t = row & (Tdim - 1);
  int b = row >> 11;
  const float* p = src + (size_t)row * (nh * 128) + h * 128;
  float v = p[d];
  float o;
  if (d < 64) {
    float c = cs[t * 64 + d], s = sn[t * 64 + d];
    o = (d < 32) ? (v * c - p[d + 32] * s) : (v * c + p[d - 32] * s);
  } else o = v;
  size_t oi = (((size_t)(b * nh + h)) * Tdim + t) * 128 + d;
  unsigned short hb = f2bf(o);
  hi[oi] = hb;
  lo[oi] = f2bf(o - bf2f(hb));
}

// ---------------- v: (b*T, 512) fp32 -> vt (b,g,d,t) bf16 ----------------
__global__ void transpose_v_kernel(const float* __restrict__ vtmp, unsigned short* __restrict__ vt) {
  __shared__ float tile[32][33];
  int bg = blockIdx.x;            // b*HKV+g
  int t0 = blockIdx.y * 32, d0 = blockIdx.z * 32;
  int b = bg >> 2, g = bg & 3;
  int tx = threadIdx.x, ty = threadIdx.y;
#pragma unroll
  for (int i = 0; i < 32; i += 8)
    tile[ty + i][tx] = vtmp[(size_t)(b * Tdim + t0 + ty + i) * KVdim + g * 128 + d0 + tx];
  __syncthreads();
#pragma unroll
  for (int i = 0; i < 32; i += 8)
    vt[((size_t)(bg * 128 + d0 + ty + i)) * Tdim + t0 + tx] = f2bf(tile[tx][ty + i]);
}

// ---------------- fused causal GQA attention with post-softmax gate ----------------
// grid (T/64, B*H), 256 threads (4 waves x 16 q-rows). Two-pass online softmax.
// QK^T is split-precision: S = qh*kh + ql*kh + qh*kl.
__global__ __launch_bounds__(256) void attn_kernel(
    const unsigned short* __restrict__ qhi, const unsigned short* __restrict__ qlo,
    const unsigned short* __restrict__ khi, const unsigned short* __restrict__ klo,
    const unsigned short* __restrict__ vt, const float* __restrict__ gate,
    unsigned short* __restrict__ y)
{
  __shared__ alignas(16) unsigned short sKhi[64 * 136];
  __shared__ alignas(16) unsigned short sKlo[64 * 136];
  __shared__ alignas(16) unsigned short sV[128 * 72];
  __shared__ alignas(16) unsigned short sP[4][16 * 72];

  int qb = blockIdx.x, bh = blockIdx.y;
  int b = bh >> 4, h = bh & 15;
  int g = h >> 2;
  int t0 = qb * 64;
  int tid = threadIdx.x, wid = tid >> 6, lane = tid & 63;
  int ln15 = lane & 15, ko8 = (lane >> 4) * 8, ro4 = (lane >> 4) * 4;
  const float scale = 0.08838834764831845f;

  // Q fragments in registers (A-layout: row = lane&15 within wave's 16 rows)
  bf16x8 aqh[4], aql[4];
  {
    size_t qoff = ((((size_t)b * Hdim + h) * Tdim) + t0 + wid * 16 + ln15) * 128 + ko8;
#pragma unroll
    for (int kf = 0; kf < 4; ++kf) {
      aqh[kf] = *(const bf16x8*)(qhi + qoff + kf * 32);
      aql[kf] = *(const bf16x8*)(qlo + qoff + kf * 32);
    }
  }
  float thr = 1.f / (1.f + expf(-gate[h]));

  float mrow[4], lrow[4];
#pragma unroll
  for (int r = 0; r < 4; ++r) { mrow[r] = -1e30f; lrow[r] = 0.f; }

  int nkb = qb + 1;
  const unsigned short* kh_base = khi + (((size_t)b * HKVdim + g) * Tdim) * 128;
  const unsigned short* kl_base = klo + (((size_t)b * HKVdim + g) * Tdim) * 128;
  const unsigned short* v_base  = vt  + (((size_t)b * HKVdim + g) * 128) * (size_t)Tdim;

  // ---- PASS A: compute row max m and denominator l ----
  for (int kb = 0; kb < nkb; ++kb) {
#pragma unroll
    for (int it = 0; it < 4; ++it) {
      int idx = it * 256 + tid;
      int rr = idx >> 4, cc = (idx & 15) * 8;
      *(bf16x8*)&sKhi[rr * 136 + cc] = *(const bf16x8*)(kh_base + ((size_t)(kb * 64 + rr)) * 128 + cc);
      *(bf16x8*)&sKlo[rr * 136 + cc] = *(const bf16x8*)(kl_base + ((size_t)(kb * 64 + rr)) * 128 + cc);
    }
    __syncthreads();
    f32x4 s[4];
#pragma unroll
    for (int nf = 0; nf < 4; ++nf) {
      f32x4 a = {0.f, 0.f, 0.f, 0.f};
#pragma unroll
      for (int kf = 0; kf < 4; ++kf) {
        bf16x8 bh_ = *(const bf16x8*)&sKhi[(nf * 16 + ln15) * 136 + kf * 32 + ko8];
        bf16x8 bl_ = *(const bf16x8*)&sKlo[(nf * 16 + ln15) * 136 + kf * 32 + ko8];
        a = __builtin_amdgcn_mfma_f32_16x16x32_bf16(aqh[kf], bh_, a, 0, 0, 0);
        a = __builtin_amdgcn_mfma_f32_16x16x32_bf16(aql[kf], bh_, a, 0, 0, 0);
        a = __builtin_amdgcn_mfma_f32_16x16x32_bf16(aqh[kf], bl_, a, 0, 0, 0);
      }
      s[nf] = a;
    }
    float bmax[4];
#pragma unroll
    for (int r = 0; r < 4; ++r) bmax[r] = -1e30f;
#pragma unroll
    for (int nf = 0; nf < 4; ++nf) {
      int tk = kb * 64 + nf * 16 + ln15;
#pragma unroll
      for (int r = 0; r < 4; ++r) {
        int tq = t0 + wid * 16 + ro4 + r;
        float sv = s[nf][r] * scale;
        sv = (tk <= tq) ? sv : -1e30f;
        s[nf][r] = sv;
        bmax[r] = fmaxf(bmax[r], sv);
      }
    }
#pragma unroll
    for (int r = 0; r < 4; ++r) {
#pragma unroll
      for (int off = 1; off < 16; off <<= 1)
        bmax[r] = fmaxf(bmax[r], __shfl_xor(bmax[r], off));
      float mn = fmaxf(mrow[r], bmax[r]);
      float es = 0.f;
#pragma unroll
      for (int nf = 0; nf < 4; ++nf) es += __expf(s[nf][r] - mn);
#pragma unroll
      for (int off = 1; off < 16; off <<= 1) es += __shfl_xor(es, off);
      lrow[r] = lrow[r] * __expf(mrow[r] - mn) + es;
      mrow[r] = mn;
    }
    __syncthreads();
  }

  // ---- PASS B: recompute S, gate, PV ----
  f32x4 yacc[8];
#pragma unroll
  for (int n = 0; n < 8; ++n) yacc[n] = f32x4{0.f, 0.f, 0.f, 0.f};

  for (int kb = 0; kb < nkb; ++kb) {
#pragma unroll
    for (int it = 0; it < 4; ++it) {
      int idx = it * 256 + tid;
      int rr = idx >> 4, cc = (idx & 15) * 8;
      *(bf16x8*)&sKhi[rr * 136 + cc] = *(const bf16x8*)(kh_base + ((size_t)(kb * 64 + rr)) * 128 + cc);
      *(bf16x8*)&sKlo[rr * 136 + cc] = *(const bf16x8*)(kl_base + ((size_t)(kb * 64 + rr)) * 128 + cc);
    }
#pragma unroll
    for (int it = 0; it < 4; ++it) {
      int idx = it * 256 + tid;
      int dd = idx >> 3, cc = (idx & 7) * 8;
      *(bf16x8*)&sV[dd * 72 + cc] = *(const bf16x8*)(v_base + (size_t)dd * Tdim + kb * 64 + cc);
    }
    __syncthreads();
#pragma unroll
    for (int nf = 0; nf < 4; ++nf) {
      f32x4 a = {0.f, 0.f, 0.f, 0.f};
#pragma unroll
      for (int kf = 0; kf < 4; ++kf) {
        bf16x8 bh_ = *(const bf16x8*)&sKhi[(nf * 16 + ln15) * 136 + kf * 32 + ko8];
        bf16x8 bl_ = *(const bf16x8*)&sKlo[(nf * 16 + ln15) * 136 + kf * 32 + ko8];
        a = __builtin_amdgcn_mfma_f32_16x16x32_bf16(aqh[kf], bh_, a, 0, 0, 0);
        a = __builtin_amdgcn_mfma_f32_16x16x32_bf16(aql[kf], bh_, a, 0, 0, 0);
        a = __builtin_amdgcn_mfma_f32_16x16x32_bf16(aqh[kf], bl_, a, 0, 0, 0);
      }
      int tk = kb * 64 + nf * 16 + ln15;
#pragma unroll
      for (int r = 0; r < 4; ++r) {
        int tq = t0 + wid * 16 + ro4 + r;
        float p = 0.f;
        if (tk <= tq) {
          p = __expf(a[r] * scale - mrow[r]);
          if (p < thr * lrow[r]) p = 0.f;   // gate: att = p/l >= thr
        }
        sP[wid][(ro4 + r) * 72 + nf * 16 + ln15] = f2bf(p);
      }
    }
    __syncthreads();
#pragma unroll
    for (int kc = 0; kc < 2; ++kc) {
      bf16x8 pa = *(const bf16x8*)&sP[wid][ln15 * 72 + kc * 32 + ko8];
#pragma unroll
      for (int nf2 = 0; nf2 < 8; ++nf2) {
        bf16x8 vb = *(const bf16x8*)&sV[(nf2 * 16 + ln15) * 72 + kc * 32 + ko8];
        yacc[nf2] = __builtin_amdgcn_mfma_f32_16x16x32_bf16(pa, vb, yacc[nf2], 0, 0, 0);
      }
    }
    __syncthreads();
  }

  // epilogue: y (b,t,h,d) bf16
#pragma unroll
  for (int r = 0; r < 4; ++r) {
    int tq = t0 + wid * 16 + ro4 + r;
    float invl = 1.f / lrow[r];
    size_t base = ((size_t)(b * Tdim + tq)) * Cdim + h * 128;
#pragma unroll
    for (int nf2 = 0; nf2 < 8; ++nf2)
      y[base + nf2 * 16 + ln15] = f2bf(yacc[nf2][r] * invl);
  }
}

extern "C" void kernel_launch(void* const* d_in, const int* in_sizes, int n_in,
                              void* d_out, int out_size, void* d_ws, size_t ws_size,
                              hipStream_t stream)
{
  (void)in_sizes; (void)n_in; (void)out_size; (void)ws_size;
  const float* x    = (const float*)d_in[0];
  const float* cosT = (const float*)d_in[1];
  const float* sinT = (const float*)d_in[2];
  const float* Wq   = (const float*)d_in[3];
  const float* Wk   = (const float*)d_in[4];
  const float* Wv   = (const float*)d_in[5];
  const float* Wo   = (const float*)d_in[6];
  const float* gate = (const float*)d_in[7];
  float* out = (float*)d_out;

  char* ws = (char*)d_ws;
  size_t off = 0;
  auto alloc = [&](size_t bytes) -> char* {
    char* p = ws + off; off += (bytes + 255) & ~(size_t)255; return p;
  };
  const size_t NX = (size_t)Bdim * Tdim * Cdim;    // 8388608
  const size_t NK = (size_t)Bdim * Tdim * KVdim;   // 2097152

  unsigned short* xhi   = (unsigned short*)alloc(NX * 2);
  unsigned short* xlo   = (unsigned short*)alloc(NX * 2);
  unsigned short* WqThi = (unsigned short*)alloc((size_t)Cdim * Cdim * 2);
  unsigned short* WqTlo = (unsigned short*)alloc((size_t)Cdim * Cdim * 2);
  unsigned short* WkThi = (unsigned short*)alloc((size_t)Cdim * KVdim * 2);
  unsigned short* WkTlo = (unsigned short*)alloc((size_t)Cdim * KVdim * 2);
  unsigned short* WvThi = (unsigned short*)alloc((size_t)Cdim * KVdim * 2);
  unsigned short* WoThi = (unsigned short*)alloc((size_t)Cdim * Cdim * 2);
  // shared fp32 temp region (33.5 MB): qtmp first; after rope_q it is reused
  // as {ktmp [0,8.4M), vtmp [8.4,16.8M), yb [16.8,33.6M)} — stream-ordered, safe.
  char* tmpR = alloc(NX * 4);
  float* qtmp = (float*)tmpR;
  float* ktmp = (float*)tmpR;
  float* vtmp = (float*)(tmpR + NK * 4);
  unsigned short* yb = (unsigned short*)(tmpR + 2 * NK * 4);
  unsigned short* qhi = (unsigned short*)alloc(NX * 2);
  unsigned short* qlo = (unsigned short*)alloc(NX * 2);
  unsigned short* khi = (unsigned short*)alloc(NK * 2);
  unsigned short* klo = (unsigned short*)alloc(NK * 2);
  unsigned short* vtr = (unsigned short*)alloc(NK * 2);

  dim3 tb(32, 8);
  split_x_kernel<<<2048, 256, 0, stream>>>(x, xhi, xlo, (int)NX);
  transpose_split_kernel<<<dim3(64, 64), tb, 0, stream>>>(Wq, WqThi, WqTlo, Cdim, Cdim);
  transpose_split_kernel<<<dim3(64, 16), tb, 0, stream>>>(Wk, WkThi, WkTlo, Cdim, KVdim);
  transpose_split_kernel<<<dim3(64, 16), tb, 0, stream>>>(Wv, WvThi, nullptr, Cdim, KVdim);
  transpose_split_kernel<<<dim3(64, 64), tb, 0, stream>>>(Wo, WoThi, nullptr, Cdim, Cdim);

  // q = x@Wq, split-3 for fp32-like precision
  gemm_bt_kernel<<<dim3(32, 16), 256, 0, stream>>>(xhi, WqThi, qtmp, 4096, 2048, 2048, 0);
  gemm_bt_kernel<<<dim3(32, 16), 256, 0, stream>>>(xhi, WqTlo, qtmp, 4096, 2048, 2048, 1);
  gemm_bt_kernel<<<dim3(32, 16), 256, 0, stream>>>(xlo, WqThi, qtmp, 4096, 2048, 2048, 1);
  rope_kernel<<<dim3(4096, 16), 128, 0, stream>>>(qtmp, cosT, sinT, qhi, qlo, Hdim);

  // k = x@Wk, split-3
  gemm_bt_kernel<<<dim3(32, 4), 256, 0, stream>>>(xhi, WkThi, ktmp, 4096, 512, 2048, 0);
  gemm_bt_kernel<<<dim3(32, 4), 256, 0, stream>>>(xhi, WkTlo, ktmp, 4096, 512, 2048, 1);
  gemm_bt_kernel<<<dim3(32, 4), 256, 0, stream>>>(xlo, WkThi, ktmp, 4096, 512, 2048, 1);
  rope_kernel<<<dim3(4096, 4), 128, 0, stream>>>(ktmp, cosT, sinT, khi, klo, HKVdim);

  // v = x@Wv, plain bf16
  gemm_bt_kernel<<<dim3(32, 4), 256, 0, stream>>>(xhi, WvThi, vtmp, 4096, 512, 2048, 0);
  transpose_v_kernel<<<dim3(8, 64, 4), tb, 0, stream>>>(vtmp, vtr);

  attn_kernel<<<dim3(32, 32), 256, 0, stream>>>(qhi, qlo, khi, klo, vtr, gate, yb);

  gemm_bt_kernel<<<dim3(32, 16), 256, 0, stream>>>(yb, WoThi, out, 4096, 2048, 2048, 0);
}

// Round 2
// 818.018 us; speedup vs baseline: 1.0944x; 1.0944x over previous
//
#include <hip/hip_runtime.h>
#include <stdint.h>

#define Bdim 2
#define Tdim 2048
#define Cdim 2048
#define Hdim 16
#define HKVdim 4
#define KVdim 512   // HKV*D

typedef __attribute__((ext_vector_type(8))) short bf16x8;
typedef __attribute__((ext_vector_type(4))) float f32x4;

#define GLOAD16(gp, lp) __builtin_amdgcn_global_load_lds( \
    (const __attribute__((address_space(1))) void*)(gp),  \
    (__attribute__((address_space(3))) void*)(lp), 16, 0, 0)

__device__ __forceinline__ unsigned short f2bf(float f) {
  union { float f; unsigned u; } a; a.f = f;
  unsigned u = a.u + 0x7FFFu + ((a.u >> 16) & 1u);   // RNE
  return (unsigned short)(u >> 16);
}
__device__ __forceinline__ float bf2f(unsigned short h) {
  union { float f; unsigned u; } a; a.u = ((unsigned)h) << 16;
  return a.f;
}

// ---------------- split x into bf16 hi/lo ----------------
__global__ void split_x_kernel(const float* __restrict__ x, unsigned short* __restrict__ hi,
                               unsigned short* __restrict__ lo, int n) {
  int i = blockIdx.x * blockDim.x + threadIdx.x;
  int stride = gridDim.x * blockDim.x;
  for (; i < n; i += stride) {
    float f = x[i];
    unsigned short hb = f2bf(f);
    hi[i] = hb;
    lo[i] = f2bf(f - bf2f(hb));
  }
}

// ---------------- transpose (K,N) fp32 -> (N,K) bf16 hi (+lo) ----------------
__global__ void transpose_split_kernel(const float* __restrict__ in, unsigned short* __restrict__ hi,
                                       unsigned short* __restrict__ lo, int K, int N) {
  __shared__ float tile[32][33];
  int k0 = blockIdx.x * 32, n0 = blockIdx.y * 32;
  int tx = threadIdx.x, ty = threadIdx.y;
#pragma unroll
  for (int i = 0; i < 32; i += 8)
    tile[ty + i][tx] = in[(size_t)(k0 + ty + i) * N + n0 + tx];
  __syncthreads();
#pragma unroll
  for (int i = 0; i < 32; i += 8) {
    float f = tile[tx][ty + i];
    size_t o = (size_t)(n0 + ty + i) * K + k0 + tx;
    unsigned short hb = f2bf(f);
    hi[o] = hb;
    if (lo) lo[o] = f2bf(f - bf2f(hb));
  }
}

// ---------------- GEMM: C(M,N) (+)= A(M,K) @ Bt(N,K)^T, bf16 in fp32 out ----------------
// m97-style: 128x128 tile, BK=32, linear LDS, global_load_lds dwordx4 staging.
__global__ __launch_bounds__(256) void gemm_bt_kernel(
    const unsigned short* __restrict__ A, const unsigned short* __restrict__ Bt,
    float* __restrict__ C, int M, int N, int K, int ldc, int accumulate)
{
  __shared__ alignas(16) unsigned short sA[128 * 32];
  __shared__ alignas(16) unsigned short sB[128 * 32];
  int tid = threadIdx.x;
  int wid = tid >> 6, lane = tid & 63;
  int bm = blockIdx.x, bn = blockIdx.y;
  int wr = wid >> 1, wc = wid & 1;
  int ln15 = lane & 15, j8 = (lane >> 4) * 8;
  int srow = lane >> 2;           // 0..15 within a 16-row chunk
  int scol = (lane & 3) * 8;      // shorts

  f32x4 acc[4][4];
#pragma unroll
  for (int m = 0; m < 4; ++m)
#pragma unroll
    for (int n = 0; n < 4; ++n)
      acc[m][n] = f32x4{0.f, 0.f, 0.f, 0.f};

  const unsigned short* a0 = A + (size_t)(bm * 128 + wid * 32 + srow) * K + scol;
  const unsigned short* b0 = Bt + (size_t)(bn * 128 + wid * 32 + srow) * K + scol;
  unsigned short* sAw = sA + (wid * 32) * 32;
  unsigned short* sBw = sB + (wid * 32) * 32;

  int nk = K >> 5;
  for (int kt = 0; kt < nk; ++kt) {
    const unsigned short* ak = a0 + kt * 32;
    const unsigned short* bk = b0 + kt * 32;
    GLOAD16(ak,            sAw);
    GLOAD16(ak + 16 * K,   sAw + 16 * 32);
    GLOAD16(bk,            sBw);
    GLOAD16(bk + 16 * K,   sBw + 16 * 32);
    __syncthreads();
    bf16x8 af[4], bfv[4];
#pragma unroll
    for (int m = 0; m < 4; ++m)
      af[m] = *(const bf16x8*)&sA[(wr * 64 + m * 16 + ln15) * 32 + j8];
#pragma unroll
    for (int n = 0; n < 4; ++n)
      bfv[n] = *(const bf16x8*)&sB[(wc * 64 + n * 16 + ln15) * 32 + j8];
#pragma unroll
    for (int m = 0; m < 4; ++m)
#pragma unroll
      for (int n = 0; n < 4; ++n)
        acc[m][n] = __builtin_amdgcn_mfma_f32_16x16x32_bf16(af[m], bfv[n], acc[m][n], 0, 0, 0);
    __syncthreads();
  }

  int orow0 = bm * 128 + wr * 64 + (lane >> 4) * 4;
  int ocol0 = bn * 128 + wc * 64 + ln15;
#pragma unroll
  for (int m = 0; m < 4; ++m)
#pragma unroll
    for (int n = 0; n < 4; ++n)
#pragma unroll
      for (int r = 0; r < 4; ++r) {
        size_t idx = (size_t)(orow0 + m * 16 + r) * ldc + ocol0 + n * 16;
        if (accumulate) C[idx] += acc[m][n][r];
        else C[idx] = acc[m][n][r];
      }
}

// ---------------- RoPE + reshape + split: rows of stride ld -> (b,h,t,d) bf16 hi/lo ----------------
__global__ void rope_kernel(const float* __restrict__ src, int ld, const float* __restrict__ cs,
                            const float* __restrict__ sn, unsigned short* __restrict__ hi,
                            unsigned short* __restrict__ lo, int nh) {
  int row = blockIdx.x;           // b*T + t
  int h = blockIdx.y;
  int d = threadIdx.x;
  int t = row & (Tdim - 1);
  int b = row >> 11;
  const float* p = src + (size_t)row * ld + h * 128;
  float v = p[d];
  float o;
  if (d < 64) {
    float c = cs[t * 64 + d], s = sn[t * 64 + d];
    o = (d < 32) ? (v * c - p[d + 32] * s) : (v * c + p[d - 32] * s);
  } else o = v;
  size_t oi = (((size_t)(b * nh + h)) * Tdim + t) * 128 + d;
  unsigned short hb = f2bf(o);
  hi[oi] = hb;
  lo[oi] = f2bf(o - bf2f(hb));
}

// ---------------- v: rows (b*T) stride ld fp32 -> vt (b,g,d,t) bf16 ----------------
__global__ void transpose_v_kernel(const float* __restrict__ vtmp, int ld, unsigned short* __restrict__ vt) {
  __shared__ float tile[32][33];
  int bg = blockIdx.x;            // b*HKV+g
  int t0 = blockIdx.y * 32, d0 = blockIdx.z * 32;
  int b = bg >> 2, g = bg & 3;
  int tx = threadIdx.x, ty = threadIdx.y;
#pragma unroll
  for (int i = 0; i < 32; i += 8)
    tile[ty + i][tx] = vtmp[(size_t)(b * Tdim + t0 + ty + i) * ld + g * 128 + d0 + tx];
  __syncthreads();
#pragma unroll
  for (int i = 0; i < 32; i += 8)
    vt[((size_t)(bg * 128 + d0 + ty + i)) * Tdim + t0 + tx] = f2bf(tile[tx][ty + i]);
}

// ---------------- fused causal GQA attention with post-softmax gate ----------------
// grid (T/128, B*H), 512 threads (8 waves x 16 q-rows). Two-pass online softmax.
// K/V staged via global_load_lds with XOR-swizzle (row&7)<<4; double-buffered prefetch.
__global__ __launch_bounds__(512, 2) void attn_kernel(
    const unsigned short* __restrict__ qhi, const unsigned short* __restrict__ qlo,
    const unsigned short* __restrict__ khi, const unsigned short* __restrict__ klo,
    const unsigned short* __restrict__ vt, const float* __restrict__ gate,
    unsigned short* __restrict__ y)
{
  __shared__ alignas(16) unsigned short sKhi[2][64 * 128];
  __shared__ alignas(16) unsigned short sKlo[2][64 * 128];
  __shared__ alignas(16) unsigned short sV[2][128 * 64];
  __shared__ alignas(16) unsigned short sP[8][16 * 72];

  int qb = (gridDim.x - 1) - blockIdx.x;     // heavy blocks first
  int bh = blockIdx.y;
  int b = bh >> 4, h = bh & 15;
  int g = h >> 2;
  int t0 = qb * 128;
  int tid = threadIdx.x, wid = tid >> 6, lane = tid & 63;
  int ln15 = lane & 15, j16 = (lane >> 4) * 16, ro4 = (lane >> 4) * 4;
  const float scale = 0.08838834764831845f;

  const unsigned short* kh_base = khi + (((size_t)b * HKVdim + g) * Tdim) * 128;
  const unsigned short* kl_base = klo + (((size_t)b * HKVdim + g) * Tdim) * 128;
  const unsigned short* v_base  = vt  + (((size_t)b * HKVdim + g) * 128) * (size_t)Tdim;

  // Q fragments in registers (A-layout)
  bf16x8 aqh[4], aql[4];
  {
    size_t qoff = ((((size_t)b * Hdim + h) * Tdim) + t0 + wid * 16 + ln15) * 128 + (lane >> 4) * 8;
#pragma unroll
    for (int kf = 0; kf < 4; ++kf) {
      aqh[kf] = *(const bf16x8*)(qhi + qoff + kf * 32);
      aql[kf] = *(const bf16x8*)(qlo + qoff + kf * 32);
    }
  }
  float thr = 1.f / (1.f + expf(-gate[h]));

  int nkb = (qb + 1) * 2;
  int tq_lo = t0 + wid * 16;      // wave's lowest q-row

  // stage K hi+lo tile (64 rows x 256B) for k-block kb into buffer buf
  auto stageK = [&](int buf, int kb) {
#pragma unroll
    for (int it = 0; it < 2; ++it) {
      int i = wid * 2 + it;                  // 16 insts over 8 waves
      int o = i * 1024 + lane * 16;          // linear LDS byte
      int row = o >> 8;                      // 0..63
      int clog = (o & 255) ^ ((row & 7) << 4);
      size_t goff = ((size_t)(kb * 64 + row)) * 256 + clog;   // bytes
      GLOAD16((const char*)kh_base + goff, (char*)sKhi[buf] + i * 1024);
      GLOAD16((const char*)kl_base + goff, (char*)sKlo[buf] + i * 1024);
    }
  };
  // stage V tile (128 rows x 128B) for k-block kb
  auto stageV = [&](int buf, int kb) {
#pragma unroll
    for (int it = 0; it < 2; ++it) {
      int i = wid * 2 + it;
      int o = i * 1024 + lane * 16;
      int row = o >> 7;                      // 0..127 (= d)
      int clog = (o & 127) ^ ((row & 7) << 4);
      size_t goff = (size_t)row * (Tdim * 2) + (size_t)kb * 128 + clog;  // bytes
      GLOAD16((const char*)v_base + goff, (char*)sV[buf] + i * 1024);
    }
  };
  // split-3 QK^T on buffer buf -> s[4] (per-lane C fragment)
  auto qk = [&](int buf, f32x4* s) {
#pragma unroll
    for (int nf = 0; nf < 4; ++nf) {
      f32x4 a = {0.f, 0.f, 0.f, 0.f};
      int krow = nf * 16 + ln15;
      int sw = (krow & 7) << 4;
#pragma unroll
      for (int kf = 0; kf < 4; ++kf) {
        int boff = (kf * 64 + j16) ^ sw;
        bf16x8 bh_ = *(const bf16x8*)((const char*)sKhi[buf] + krow * 256 + boff);
        bf16x8 bl_ = *(const bf16x8*)((const char*)sKlo[buf] + krow * 256 + boff);
        a = __builtin_amdgcn_mfma_f32_16x16x32_bf16(aqh[kf], bh_, a, 0, 0, 0);
        a = __builtin_amdgcn_mfma_f32_16x16x32_bf16(aql[kf], bh_, a, 0, 0, 0);
        a = __builtin_amdgcn_mfma_f32_16x16x32_bf16(aqh[kf], bl_, a, 0, 0, 0);
      }
      s[nf] = a;
    }
  };

  float mrow[4], lrow[4];
#pragma unroll
  for (int r = 0; r < 4; ++r) { mrow[r] = -1e30f; lrow[r] = 0.f; }

  // ---- PASS A: row max m and denominator l ----
  stageK(0, 0);
  __syncthreads();
  for (int kb = 0; kb < nkb; ++kb) {
    int buf = kb & 1;
    if (kb + 1 < nkb) stageK(buf ^ 1, kb + 1);
    if (kb * 64 <= tq_lo + 15) {             // wave-uniform; skip fully-masked
      f32x4 s[4];
      qk(buf, s);
      float bmax[4];
#pragma unroll
      for (int r = 0; r < 4; ++r) bmax[r] = -1e30f;
#pragma unroll
      for (int nf = 0; nf < 4; ++nf) {
        int tk = kb * 64 + nf * 16 + ln15;
#pragma unroll
        for (int r = 0; r < 4; ++r) {
          int tq = t0 + wid * 16 + ro4 + r;
          float sv = s[nf][r] * scale;
          sv = (tk <= tq) ? sv : -1e30f;
          s[nf][r] = sv;
          bmax[r] = fmaxf(bmax[r], sv);
        }
      }
#pragma unroll
      for (int r = 0; r < 4; ++r) {
#pragma unroll
        for (int off = 1; off < 16; off <<= 1)
          bmax[r] = fmaxf(bmax[r], __shfl_xor(bmax[r], off));
        float mn = fmaxf(mrow[r], bmax[r]);
        float es = 0.f;
#pragma unroll
        for (int nf = 0; nf < 4; ++nf) es += __expf(s[nf][r] - mn);
#pragma unroll
        for (int off = 1; off < 16; off <<= 1) es += __shfl_xor(es, off);
        lrow[r] = lrow[r] * __expf(mrow[r] - mn) + es;
        mrow[r] = mn;
      }
    }
    __syncthreads();
  }

  // ---- PASS B: recompute S, gate, PV ----
  f32x4 yacc[8];
#pragma unroll
  for (int n = 0; n < 8; ++n) yacc[n] = f32x4{0.f, 0.f, 0.f, 0.f};

  stageK(0, 0);
  stageV(0, 0);
  __syncthreads();
  for (int kb = 0; kb < nkb; ++kb) {
    int buf = kb & 1;
    if (kb + 1 < nkb) { stageK(buf ^ 1, kb + 1); stageV(buf ^ 1, kb + 1); }
    if (kb * 64 <= tq_lo + 15) {
      f32x4 s[4];
      qk(buf, s);
#pragma unroll
      for (int nf = 0; nf < 4; ++nf) {
        int tk = kb * 64 + nf * 16 + ln15;
#pragma unroll
        for (int r = 0; r < 4; ++r) {
          int tq = t0 + wid * 16 + ro4 + r;
          float p = 0.f;
          if (tk <= tq) {
            p = __expf(s[nf][r] * scale - mrow[r]);
            if (p < thr * lrow[r]) p = 0.f;   // gate: att = p/l >= thr
          }
          sP[wid][(ro4 + r) * 72 + nf * 16 + ln15] = f2bf(p);
        }
      }
      // same-wave LDS RAW: compiler inserts lgkmcnt wait
#pragma unroll
      for (int kc = 0; kc < 2; ++kc) {
        bf16x8 pa = *(const bf16x8*)&sP[wid][ln15 * 72 + kc * 32 + (lane >> 4) * 8];
#pragma unroll
        for (int nf2 = 0; nf2 < 8; ++nf2) {
          int vrow = nf2 * 16 + ln15;
          int vboff = (kc * 64 + j16) ^ ((vrow & 7) << 4);
          bf16x8 vb = *(const bf16x8*)((const char*)sV[buf] + vrow * 128 + vboff);
          yacc[nf2] = __builtin_amdgcn_mfma_f32_16x16x32_bf16(pa, vb, yacc[nf2], 0, 0, 0);
        }
      }
    }
    __syncthreads();
  }

  // epilogue: y (b,t,h,d) bf16
#pragma unroll
  for (int r = 0; r < 4; ++r) {
    int tq = t0 + wid * 16 + ro4 + r;
    float invl = 1.f / lrow[r];
    size_t base = ((size_t)(b * Tdim + tq)) * Cdim + h * 128;
#pragma unroll
    for (int nf2 = 0; nf2 < 8; ++nf2)
      y[base + nf2 * 16 + ln15] = f2bf(yacc[nf2][r] * invl);
  }
}

extern "C" void kernel_launch(void* const* d_in, const int* in_sizes, int n_in,
                              void* d_out, int out_size, void* d_ws, size_t ws_size,
                              hipStream_t stream)
{
  (void)in_sizes; (void)n_in; (void)out_size; (void)ws_size;
  const float* x    = (const float*)d_in[0];
  const float* cosT = (const float*)d_in[1];
  const float* sinT = (const float*)d_in[2];
  const float* Wq   = (const float*)d_in[3];
  const float* Wk   = (const float*)d_in[4];
  const float* Wv   = (const float*)d_in[5];
  const float* Wo   = (const float*)d_in[6];
  const float* gate = (const float*)d_in[7];
  float* out = (float*)d_out;

  char* ws = (char*)d_ws;
  size_t off = 0;
  auto alloc = [&](size_t bytes) -> char* {
    char* p = ws + off; off += (bytes + 255) & ~(size_t)255; return p;
  };
  const size_t NX = (size_t)Bdim * Tdim * Cdim;    // 8388608
  const size_t NK = (size_t)Bdim * Tdim * KVdim;   // 2097152

  unsigned short* xhi    = (unsigned short*)alloc(NX * 2);
  unsigned short* xlo    = (unsigned short*)alloc(NX * 2);
  unsigned short* WqThi  = (unsigned short*)alloc((size_t)Cdim * Cdim * 2);
  unsigned short* WqTlo  = (unsigned short*)alloc((size_t)Cdim * Cdim * 2);
  unsigned short* WkvThi = (unsigned short*)alloc((size_t)Cdim * 1024 * 2);  // rows 0-511 WkT, 512-1023 WvT
  unsigned short* WkTlo  = (unsigned short*)alloc((size_t)Cdim * KVdim * 2);
  unsigned short* WoThi  = (unsigned short*)alloc((size_t)Cdim * Cdim * 2);
  // shared fp32 temp region (32MB): qtmp first; then {kvtmp [0,16M), yb [16,32M)}
  char* tmpR = alloc(NX * 4);
  float* qtmp  = (float*)tmpR;
  float* kvtmp = (float*)tmpR;                        // 4096 x 1024 fp32
  unsigned short* yb = (unsigned short*)(tmpR + (size_t)4096 * 1024 * 4);
  unsigned short* qhi = (unsigned short*)alloc(NX * 2);
  unsigned short* qlo = (unsigned short*)alloc(NX * 2);
  unsigned short* khi = (unsigned short*)alloc(NK * 2);
  unsigned short* klo = (unsigned short*)alloc(NK * 2);
  unsigned short* vtr = (unsigned short*)alloc(NK * 2);

  dim3 tb(32, 8);
  split_x_kernel<<<2048, 256, 0, stream>>>(x, xhi, xlo, (int)NX);
  transpose_split_kernel<<<dim3(64, 64), tb, 0, stream>>>(Wq, WqThi, WqTlo, Cdim, Cdim);
  transpose_split_kernel<<<dim3(64, 16), tb, 0, stream>>>(Wk, WkvThi, WkTlo, Cdim, KVdim);
  transpose_split_kernel<<<dim3(64, 16), tb, 0, stream>>>(Wv, WkvThi + (size_t)512 * Cdim, nullptr, Cdim, KVdim);
  transpose_split_kernel<<<dim3(64, 64), tb, 0, stream>>>(Wo, WoThi, nullptr, Cdim, Cdim);

  // q = x@Wq, split-3
  gemm_bt_kernel<<<dim3(32, 16), 256, 0, stream>>>(xhi, WqThi, qtmp, 4096, 2048, 2048, 2048, 0);
  gemm_bt_kernel<<<dim3(32, 16), 256, 0, stream>>>(xhi, WqTlo, qtmp, 4096, 2048, 2048, 2048, 1);
  gemm_bt_kernel<<<dim3(32, 16), 256, 0, stream>>>(xlo, WqThi, qtmp, 4096, 2048, 2048, 2048, 1);
  rope_kernel<<<dim3(4096, 16), 128, 0, stream>>>(qtmp, 2048, cosT, sinT, qhi, qlo, Hdim);

  // k|v = x@[Wk Wv] (hi term fused, N=1024), then K-only lo terms
  gemm_bt_kernel<<<dim3(32, 8), 256, 0, stream>>>(xhi, WkvThi, kvtmp, 4096, 1024, 2048, 1024, 0);
  gemm_bt_kernel<<<dim3(32, 4), 256, 0, stream>>>(xhi, WkTlo,  kvtmp, 4096, 512, 2048, 1024, 1);
  gemm_bt_kernel<<<dim3(32, 4), 256, 0, stream>>>(xlo, WkvThi, kvtmp, 4096, 512, 2048, 1024, 1);
  rope_kernel<<<dim3(4096, 4), 128, 0, stream>>>(kvtmp, 1024, cosT, sinT, khi, klo, HKVdim);
  transpose_v_kernel<<<dim3(8, 64, 4), tb, 0, stream>>>(kvtmp + 512, 1024, vtr);

  attn_kernel<<<dim3(16, 32), 512, 0, stream>>>(qhi, qlo, khi, klo, vtr, gate, yb);

  gemm_bt_kernel<<<dim3(32, 16), 256, 0, stream>>>(yb, WoThi, out, 4096, 2048, 2048, 2048, 0);
}

// Round 4
// 479.671 us; speedup vs baseline: 1.8663x; 1.7054x over previous
//
#include <hip/hip_runtime.h>
#include <stdint.h>

#define Bdim 2
#define Tdim 2048
#define Cdim 2048
#define Hdim 16
#define HKVdim 4
#define KVdim 512   // HKV*D
#define KT 32       // attn k-tile rows

typedef __attribute__((ext_vector_type(8))) short bf16x8;
typedef __attribute__((ext_vector_type(4))) float f32x4;

#define GLOAD16(gp, lp) __builtin_amdgcn_global_load_lds( \
    (const __attribute__((address_space(1))) void*)(gp),  \
    (__attribute__((address_space(3))) void*)(lp), 16, 0, 0)

__device__ __forceinline__ unsigned short f2bf(float f) {
  union { float f; unsigned u; } a; a.f = f;
  unsigned u = a.u + 0x7FFFu + ((a.u >> 16) & 1u);   // RNE
  return (unsigned short)(u >> 16);
}
__device__ __forceinline__ float bf2f(unsigned short h) {
  union { float f; unsigned u; } a; a.u = ((unsigned)h) << 16;
  return a.f;
}

// ---------------- split x into bf16 hi/lo ----------------
__global__ void split_x_kernel(const float* __restrict__ x, unsigned short* __restrict__ hi,
                               unsigned short* __restrict__ lo, int n) {
  int i = blockIdx.x * blockDim.x + threadIdx.x;
  int stride = gridDim.x * blockDim.x;
  for (; i < n; i += stride) {
    float f = x[i];
    unsigned short hb = f2bf(f);
    hi[i] = hb;
    lo[i] = f2bf(f - bf2f(hb));
  }
}

// ---------------- transpose (K,N) fp32 -> (N,K) bf16 hi (+lo) ----------------
__global__ void transpose_split_kernel(const float* __restrict__ in, unsigned short* __restrict__ hi,
                                       unsigned short* __restrict__ lo, int K, int N) {
  __shared__ float tile[32][33];
  int k0 = blockIdx.x * 32, n0 = blockIdx.y * 32;
  int tx = threadIdx.x, ty = threadIdx.y;
#pragma unroll
  for (int i = 0; i < 32; i += 8)
    tile[ty + i][tx] = in[(size_t)(k0 + ty + i) * N + n0 + tx];
  __syncthreads();
#pragma unroll
  for (int i = 0; i < 32; i += 8) {
    float f = tile[tx][ty + i];
    size_t o = (size_t)(n0 + ty + i) * K + k0 + tx;
    unsigned short hb = f2bf(f);
    hi[o] = hb;
    if (lo) lo[o] = f2bf(f - bf2f(hb));
  }
}

// ---------------- mixed GEMM: C(M,N) = A @ Bt^T ----------------
// Blocks with bn*128 < N3: 3-term split (Ah*B3h + Al*B3h + Ah*B3l).
// Other blocks: 1-term (Ah*B1h), B1h col base = bn*128 - N3.
// 128x128 tile, BK=32, linear LDS, global_load_lds dwordx4 staging.
__global__ __launch_bounds__(256) void gemm_mix_kernel(
    const unsigned short* __restrict__ Ah, const unsigned short* __restrict__ Al,
    const unsigned short* __restrict__ B3h, const unsigned short* __restrict__ B3l,
    const unsigned short* __restrict__ B1h, int N3,
    float* __restrict__ C, int K, int ldc)
{
  __shared__ alignas(16) unsigned short sAh[128 * 32];
  __shared__ alignas(16) unsigned short sAl[128 * 32];
  __shared__ alignas(16) unsigned short sBh[128 * 32];
  __shared__ alignas(16) unsigned short sBl[128 * 32];
  int tid = threadIdx.x;
  int wid = tid >> 6, lane = tid & 63;
  int bm = blockIdx.x, bn = blockIdx.y;
  int wr = wid >> 1, wc = wid & 1;
  int ln15 = lane & 15, j8 = (lane >> 4) * 8;
  int srow = lane >> 2;           // 0..15
  int scol = (lane & 3) * 8;      // shorts
  bool three = (bn * 128) < N3;

  f32x4 acc[4][4];
#pragma unroll
  for (int m = 0; m < 4; ++m)
#pragma unroll
    for (int n = 0; n < 4; ++n)
      acc[m][n] = f32x4{0.f, 0.f, 0.f, 0.f};

  const unsigned short* a0 = Ah + (size_t)(bm * 128 + wid * 32 + srow) * K + scol;
  const unsigned short* a1 = Al + (size_t)(bm * 128 + wid * 32 + srow) * K + scol;
  int brow = three ? bn * 128 : bn * 128 - N3;
  const unsigned short* bsrc_h = three ? B3h : B1h;
  const unsigned short* b0 = bsrc_h + (size_t)(brow + wid * 32 + srow) * K + scol;
  const unsigned short* b1 = B3l + (size_t)(brow + wid * 32 + srow) * K + scol;
  unsigned short* sAhw = sAh + wid * 32 * 32;
  unsigned short* sAlw = sAl + wid * 32 * 32;
  unsigned short* sBhw = sBh + wid * 32 * 32;
  unsigned short* sBlw = sBl + wid * 32 * 32;

  int nk = K >> 5;
  if (three) {
    for (int kt = 0; kt < nk; ++kt) {
      const unsigned short* ak = a0 + kt * 32;
      const unsigned short* alk = a1 + kt * 32;
      const unsigned short* bk = b0 + kt * 32;
      const unsigned short* blk = b1 + kt * 32;
      GLOAD16(ak,          sAhw);
      GLOAD16(ak + 16 * K, sAhw + 16 * 32);
      GLOAD16(alk,          sAlw);
      GLOAD16(alk + 16 * K, sAlw + 16 * 32);
      GLOAD16(bk,          sBhw);
      GLOAD16(bk + 16 * K, sBhw + 16 * 32);
      GLOAD16(blk,          sBlw);
      GLOAD16(blk + 16 * K, sBlw + 16 * 32);
      __syncthreads();
      bf16x8 afh[4], afl[4], bfh[4], bfl[4];
#pragma unroll
      for (int m = 0; m < 4; ++m) {
        afh[m] = *(const bf16x8*)&sAh[(wr * 64 + m * 16 + ln15) * 32 + j8];
        afl[m] = *(const bf16x8*)&sAl[(wr * 64 + m * 16 + ln15) * 32 + j8];
      }
#pragma unroll
      for (int n = 0; n < 4; ++n) {
        bfh[n] = *(const bf16x8*)&sBh[(wc * 64 + n * 16 + ln15) * 32 + j8];
        bfl[n] = *(const bf16x8*)&sBl[(wc * 64 + n * 16 + ln15) * 32 + j8];
      }
      __builtin_amdgcn_s_setprio(1);
#pragma unroll
      for (int m = 0; m < 4; ++m)
#pragma unroll
        for (int n = 0; n < 4; ++n) {
          acc[m][n] = __builtin_amdgcn_mfma_f32_16x16x32_bf16(afh[m], bfh[n], acc[m][n], 0, 0, 0);
          acc[m][n] = __builtin_amdgcn_mfma_f32_16x16x32_bf16(afl[m], bfh[n], acc[m][n], 0, 0, 0);
          acc[m][n] = __builtin_amdgcn_mfma_f32_16x16x32_bf16(afh[m], bfl[n], acc[m][n], 0, 0, 0);
        }
      __builtin_amdgcn_s_setprio(0);
      __syncthreads();
    }
  } else {
    for (int kt = 0; kt < nk; ++kt) {
      const unsigned short* ak = a0 + kt * 32;
      const unsigned short* bk = b0 + kt * 32;
      GLOAD16(ak,          sAhw);
      GLOAD16(ak + 16 * K, sAhw + 16 * 32);
      GLOAD16(bk,          sBhw);
      GLOAD16(bk + 16 * K, sBhw + 16 * 32);
      __syncthreads();
      bf16x8 afh[4], bfh[4];
#pragma unroll
      for (int m = 0; m < 4; ++m)
        afh[m] = *(const bf16x8*)&sAh[(wr * 64 + m * 16 + ln15) * 32 + j8];
#pragma unroll
      for (int n = 0; n < 4; ++n)
        bfh[n] = *(const bf16x8*)&sBh[(wc * 64 + n * 16 + ln15) * 32 + j8];
      __builtin_amdgcn_s_setprio(1);
#pragma unroll
      for (int m = 0; m < 4; ++m)
#pragma unroll
        for (int n = 0; n < 4; ++n)
          acc[m][n] = __builtin_amdgcn_mfma_f32_16x16x32_bf16(afh[m], bfh[n], acc[m][n], 0, 0, 0);
      __builtin_amdgcn_s_setprio(0);
      __syncthreads();
    }
  }

  int orow0 = bm * 128 + wr * 64 + (lane >> 4) * 4;
  int ocol0 = bn * 128 + wc * 64 + ln15;
#pragma unroll
  for (int m = 0; m < 4; ++m)
#pragma unroll
    for (int n = 0; n < 4; ++n)
#pragma unroll
      for (int r = 0; r < 4; ++r)
        C[(size_t)(orow0 + m * 16 + r) * ldc + ocol0 + n * 16] = acc[m][n][r];
}

// ---------------- RoPE + reshape + split ----------------
__global__ void rope_kernel(const float* __restrict__ src, int ld, const float* __restrict__ cs,
                            const float* __restrict__ sn, unsigned short* __restrict__ hi,
                            unsigned short* __restrict__ lo, int nh) {
  int row = blockIdx.x;           // b*T + t
  int h = blockIdx.y;
  int d = threadIdx.x;
  int t = row & (Tdim - 1);
  int b = row >> 11;
  const float* p = src + (size_t)row * ld + h * 128;
  float v = p[d];
  float o;
  if (d < 64) {
    float c = cs[t * 64 + d], s = sn[t * 64 + d];
    o = (d < 32) ? (v * c - p[d + 32] * s) : (v * c + p[d - 32] * s);
  } else o = v;
  size_t oi = (((size_t)(b * nh + h)) * Tdim + t) * 128 + d;
  unsigned short hb = f2bf(o);
  hi[oi] = hb;
  lo[oi] = f2bf(o - bf2f(hb));
}

// ---------------- v: rows (b*T) stride ld fp32 -> vt (b,g,d,t) bf16 ----------------
__global__ void transpose_v_kernel(const float* __restrict__ vtmp, int ld, unsigned short* __restrict__ vt) {
  __shared__ float tile[32][33];
  int bg = blockIdx.x;            // b*HKV+g
  int t0 = blockIdx.y * 32, d0 = blockIdx.z * 32;
  int b = bg >> 2, g = bg & 3;
  int tx = threadIdx.x, ty = threadIdx.y;
#pragma unroll
  for (int i = 0; i < 32; i += 8)
    tile[ty + i][tx] = vtmp[(size_t)(b * Tdim + t0 + ty + i) * ld + g * 128 + d0 + tx];
  __syncthreads();
#pragma unroll
  for (int i = 0; i < 32; i += 8)
    vt[((size_t)(bg * 128 + d0 + ty + i)) * Tdim + t0 + tx] = f2bf(tile[tx][ty + i]);
}

// ---------------- fused causal GQA attention with post-softmax gate ----------------
// grid (T/128, B*H), 512 threads (8 waves x 16 q-rows). Two-pass, per-lane deferred
// softmax, log-space gate, pass-B block skipping via pass-A per-block score max.
// C-layout: col(lane&15)=k axis, (lane>>4)*4+r = q-row. Row merge = shfl over bits 0-3.
__global__ __launch_bounds__(512, 4) void attn_kernel(
    const unsigned short* __restrict__ qhi, const unsigned short* __restrict__ qlo,
    const unsigned short* __restrict__ khi, const unsigned short* __restrict__ klo,
    const unsigned short* __restrict__ vt, const float* __restrict__ gate,
    unsigned short* __restrict__ y)
{
  __shared__ alignas(16) unsigned short sKh[2][KT * 128];
  __shared__ alignas(16) unsigned short sKl[2][KT * 128];
  __shared__ alignas(16) unsigned short sV[2][128 * KT];
  __shared__ alignas(16) unsigned short sP[8][16 * 40];
  __shared__ float sBM[8][64];

  int qb = (gridDim.x - 1) - blockIdx.x;     // heavy blocks first
  int bh = blockIdx.y;
  int b = bh >> 4, h = bh & 15;
  int g = h >> 2;
  int t0 = qb * 128;
  int tid = threadIdx.x, wid = tid >> 6, lane = tid & 63;
  int ln15 = lane & 15, j16 = (lane >> 4) * 16, ro4 = (lane >> 4) * 4;
  const float scale = 0.08838834764831845f;

  const unsigned short* kh_base = khi + (((size_t)b * HKVdim + g) * Tdim) * 128;
  const unsigned short* kl_base = klo + (((size_t)b * HKVdim + g) * Tdim) * 128;
  const unsigned short* v_base  = vt  + (((size_t)b * HKVdim + g) * 128) * (size_t)Tdim;

  // Q fragments (A-layout)
  bf16x8 aqh[4], aql[4];
  {
    size_t qoff = ((((size_t)b * Hdim + h) * Tdim) + t0 + wid * 16 + ln15) * 128 + (lane >> 4) * 8;
#pragma unroll
    for (int kf = 0; kf < 4; ++kf) {
      aqh[kf] = *(const bf16x8*)(qhi + qoff + kf * 32);
      aql[kf] = *(const bf16x8*)(qlo + qoff + kf * 32);
    }
  }
  float thr = 1.f / (1.f + expf(-gate[h]));

  int nkb = (qb + 1) * 4;
  int tq_lo = t0 + wid * 16;

  auto stageK = [&](int buf, int kb) {
    int o = wid * 1024 + lane * 16;
    int row = o >> 8;                        // 0..31
    int col = (o & 255) ^ ((row & 7) << 4);
    size_t goff = ((size_t)(kb * KT + row)) * 256 + col;     // bytes
    GLOAD16((const char*)kh_base + goff, (char*)sKh[buf] + wid * 1024);
    GLOAD16((const char*)kl_base + goff, (char*)sKl[buf] + wid * 1024);
  };
  auto stageV = [&](int buf, int kb) {
    int o = wid * 1024 + lane * 16;
    int row = o >> 6;                        // 0..127 (= d)
    int col = (o & 63) ^ (((row ^ (row >> 2)) & 3) << 4);
    size_t goff = (size_t)row * (Tdim * 2) + (size_t)kb * 64 + col;  // bytes
    GLOAD16((const char*)v_base + goff, (char*)sV[buf] + wid * 1024);
  };
  auto qk = [&](int buf, f32x4* s) {
    __builtin_amdgcn_s_setprio(1);
#pragma unroll
    for (int nf = 0; nf < 2; ++nf) {
      f32x4 a = {0.f, 0.f, 0.f, 0.f};
      int krow = nf * 16 + ln15;
      int sw = (krow & 7) << 4;
#pragma unroll
      for (int kf = 0; kf < 4; ++kf) {
        int boff = (kf * 64 + j16) ^ sw;
        bf16x8 bh_ = *(const bf16x8*)((const char*)sKh[buf] + krow * 256 + boff);
        bf16x8 bl_ = *(const bf16x8*)((const char*)sKl[buf] + krow * 256 + boff);
        a = __builtin_amdgcn_mfma_f32_16x16x32_bf16(aqh[kf], bh_, a, 0, 0, 0);
        a = __builtin_amdgcn_mfma_f32_16x16x32_bf16(aql[kf], bh_, a, 0, 0, 0);
        a = __builtin_amdgcn_mfma_f32_16x16x32_bf16(aqh[kf], bl_, a, 0, 0, 0);
      }
      s[nf] = a;
    }
    __builtin_amdgcn_s_setprio(0);
  };

  float mloc[4], lloc[4];
#pragma unroll
  for (int r = 0; r < 4; ++r) { mloc[r] = -1e30f; lloc[r] = 0.f; }

  // ---- PASS A: per-lane online (m,l); record per-block wave score max ----
  stageK(0, 0);
  __syncthreads();
  for (int kb = 0; kb < nkb; ++kb) {
    int buf = kb & 1;
    if (kb + 1 < nkb) stageK(buf ^ 1, kb + 1);
    if (kb * KT <= tq_lo + 15) {
      f32x4 s[2];
      qk(buf, s);
#pragma unroll
      for (int nf = 0; nf < 2; ++nf) {
        int tk = kb * KT + nf * 16 + ln15;
#pragma unroll
        for (int r = 0; r < 4; ++r) {
          int tq = t0 + wid * 16 + ro4 + r;
          float sv = s[nf][r] * scale;
          s[nf][r] = (tk <= tq) ? sv : -1e30f;
        }
      }
      float wmax = -1e30f;
#pragma unroll
      for (int r = 0; r < 4; ++r) {
        float mx = fmaxf(s[0][r], s[1][r]);
        wmax = fmaxf(wmax, mx);
        float mn = fmaxf(mloc[r], mx);
        lloc[r] = lloc[r] * __expf(mloc[r] - mn) + __expf(s[0][r] - mn) + __expf(s[1][r] - mn);
        mloc[r] = mn;
      }
#pragma unroll
      for (int off = 1; off < 64; off <<= 1)
        wmax = fmaxf(wmax, __shfl_xor(wmax, off));
      if (lane == 0) sBM[wid][kb] = wmax;
    }
    __syncthreads();
  }

  // merge per-lane (m,l) across k-residues: bits 0-3 of lane (FIX: was 16/32)
  float mrow[4], lrow[4], lgate[4];
#pragma unroll
  for (int r = 0; r < 4; ++r) {
    float m = mloc[r], l = lloc[r];
#pragma unroll
    for (int off = 1; off < 16; off <<= 1) {
      float mo = __shfl_xor(m, off);
      float lo2 = __shfl_xor(l, off);
      float mn = fmaxf(m, mo);
      l = l * __expf(m - mn) + lo2 * __expf(mo - mn);
      m = mn;
    }
    mrow[r] = m; lrow[r] = l;
    lgate[r] = __logf(thr * l) + m;          // keep p iff s >= lgate
  }
  float lgmin = fminf(fminf(lgate[0], lgate[1]), fminf(lgate[2], lgate[3]));
#pragma unroll
  for (int off = 1; off < 64; off <<= 1)
    lgmin = fminf(lgmin, __shfl_xor(lgmin, off));

  // ---- PASS B: QK only on live blocks, gate, PV ----
  f32x4 yacc[8];
#pragma unroll
  for (int n = 0; n < 8; ++n) yacc[n] = f32x4{0.f, 0.f, 0.f, 0.f};

  stageK(0, 0);
  stageV(0, 0);
  __syncthreads();
  for (int kb = 0; kb < nkb; ++kb) {
    int buf = kb & 1;
    if (kb + 1 < nkb) { stageK(buf ^ 1, kb + 1); stageV(buf ^ 1, kb + 1); }
    if (kb * KT <= tq_lo + 15 && sBM[wid][kb] >= lgmin) {
      f32x4 s[2];
      qk(buf, s);
      bool anyk = false;
      float pv[2][4];
#pragma unroll
      for (int nf = 0; nf < 2; ++nf) {
        int tk = kb * KT + nf * 16 + ln15;
#pragma unroll
        for (int r = 0; r < 4; ++r) {
          int tq = t0 + wid * 16 + ro4 + r;
          float sv = s[nf][r] * scale;
          float p = 0.f;
          if (tk <= tq && sv >= lgate[r]) {
            p = __expf(sv - mrow[r]);
            anyk = true;
          }
          pv[nf][r] = p;
        }
      }
      if (__any(anyk)) {
#pragma unroll
        for (int nf = 0; nf < 2; ++nf)
#pragma unroll
          for (int r = 0; r < 4; ++r)
            sP[wid][(ro4 + r) * 40 + nf * 16 + ln15] = f2bf(pv[nf][r]);
        __builtin_amdgcn_s_setprio(1);
        bf16x8 pa = *(const bf16x8*)&sP[wid][ln15 * 40 + (lane >> 4) * 8];
#pragma unroll
        for (int nf2 = 0; nf2 < 8; ++nf2) {
          int vrow = nf2 * 16 + ln15;
          int vboff = j16 ^ (((vrow ^ (vrow >> 2)) & 3) << 4);
          bf16x8 vb = *(const bf16x8*)((const char*)sV[buf] + vrow * 64 + vboff);
          yacc[nf2] = __builtin_amdgcn_mfma_f32_16x16x32_bf16(pa, vb, yacc[nf2], 0, 0, 0);
        }
        __builtin_amdgcn_s_setprio(0);
      }
    }
    __syncthreads();
  }

  // epilogue: y (b,t,h,d) bf16
#pragma unroll
  for (int r = 0; r < 4; ++r) {
    int tq = t0 + wid * 16 + ro4 + r;
    float invl = 1.f / lrow[r];
    size_t base = ((size_t)(b * Tdim + tq)) * Cdim + h * 128;
#pragma unroll
    for (int nf2 = 0; nf2 < 8; ++nf2)
      y[base + nf2 * 16 + ln15] = f2bf(yacc[nf2][r] * invl);
  }
}

extern "C" void kernel_launch(void* const* d_in, const int* in_sizes, int n_in,
                              void* d_out, int out_size, void* d_ws, size_t ws_size,
                              hipStream_t stream)
{
  (void)in_sizes; (void)n_in; (void)out_size; (void)ws_size;
  const float* x    = (const float*)d_in[0];
  const float* cosT = (const float*)d_in[1];
  const float* sinT = (const float*)d_in[2];
  const float* Wq   = (const float*)d_in[3];
  const float* Wk   = (const float*)d_in[4];
  const float* Wv   = (const float*)d_in[5];
  const float* Wo   = (const float*)d_in[6];
  const float* gate = (const float*)d_in[7];
  float* out = (float*)d_out;

  char* ws = (char*)d_ws;
  size_t off = 0;
  auto alloc = [&](size_t bytes) -> char* {
    char* p = ws + off; off += (bytes + 255) & ~(size_t)255; return p;
  };
  const size_t NX = (size_t)Bdim * Tdim * Cdim;    // 8388608
  const size_t NK = (size_t)Bdim * Tdim * KVdim;   // 2097152

  unsigned short* xhi   = (unsigned short*)alloc(NX * 2);
  unsigned short* xlo   = (unsigned short*)alloc(NX * 2);
  unsigned short* WqThi = (unsigned short*)alloc((size_t)Cdim * Cdim * 2);
  unsigned short* WqTlo = (unsigned short*)alloc((size_t)Cdim * Cdim * 2);
  unsigned short* WkThi = (unsigned short*)alloc((size_t)Cdim * KVdim * 2);
  unsigned short* WkTlo = (unsigned short*)alloc((size_t)Cdim * KVdim * 2);
  unsigned short* WvThi = (unsigned short*)alloc((size_t)Cdim * KVdim * 2);
  unsigned short* WoThi = (unsigned short*)alloc((size_t)Cdim * Cdim * 2);
  // shared fp32 temp region (32MB): qtmp first; then {kvtmp [0,16M), yb [16,32M)}
  char* tmpR = alloc(NX * 4);
  float* qtmp  = (float*)tmpR;
  float* kvtmp = (float*)tmpR;                        // 4096 x 1024 fp32
  unsigned short* yb = (unsigned short*)(tmpR + (size_t)4096 * 1024 * 4);
  unsigned short* qhi = (unsigned short*)alloc(NX * 2);
  unsigned short* qlo = (unsigned short*)alloc(NX * 2);
  unsigned short* khi = (unsigned short*)alloc(NK * 2);
  unsigned short* klo = (unsigned short*)alloc(NK * 2);
  unsigned short* vtr = (unsigned short*)alloc(NK * 2);

  dim3 tb(32, 8);
  split_x_kernel<<<2048, 256, 0, stream>>>(x, xhi, xlo, (int)NX);
  transpose_split_kernel<<<dim3(64, 64), tb, 0, stream>>>(Wq, WqThi, WqTlo, Cdim, Cdim);
  transpose_split_kernel<<<dim3(64, 16), tb, 0, stream>>>(Wk, WkThi, WkTlo, Cdim, KVdim);
  transpose_split_kernel<<<dim3(64, 16), tb, 0, stream>>>(Wv, WvThi, nullptr, Cdim, KVdim);
  transpose_split_kernel<<<dim3(64, 64), tb, 0, stream>>>(Wo, WoThi, nullptr, Cdim, Cdim);

  // q = x@Wq (split-3 fused)
  gemm_mix_kernel<<<dim3(32, 16), 256, 0, stream>>>(
      xhi, xlo, WqThi, WqTlo, WqThi, 2048, qtmp, 2048, 2048);
  rope_kernel<<<dim3(4096, 16), 128, 0, stream>>>(qtmp, 2048, cosT, sinT, qhi, qlo, Hdim);

  // k|v: cols 0-511 = x@Wk (split-3), cols 512-1023 = x@Wv (1-term)
  gemm_mix_kernel<<<dim3(32, 8), 256, 0, stream>>>(
      xhi, xlo, WkThi, WkTlo, WvThi, 512, kvtmp, 2048, 1024);
  rope_kernel<<<dim3(4096, 4), 128, 0, stream>>>(kvtmp, 1024, cosT, sinT, khi, klo, HKVdim);
  transpose_v_kernel<<<dim3(8, 64, 4), tb, 0, stream>>>(kvtmp + 512, 1024, vtr);

  attn_kernel<<<dim3(16, 32), 512, 0, stream>>>(qhi, qlo, khi, klo, vtr, gate, yb);

  // out = y @ Wo (1-term)
  gemm_mix_kernel<<<dim3(32, 16), 256, 0, stream>>>(
      yb, nullptr, WoThi, WoThi, WoThi, 0, out, 2048, 2048);
}

// Round 5
// 459.070 us; speedup vs baseline: 1.9501x; 1.0449x over previous
//
#include <hip/hip_runtime.h>
#include <stdint.h>

#define Bdim 2
#define Tdim 2048
#define Cdim 2048
#define Hdim 16
#define HKVdim 4
#define KVdim 512   // HKV*D
#define KT 32       // attn k-tile rows

typedef __attribute__((ext_vector_type(8))) short bf16x8;
typedef __attribute__((ext_vector_type(4))) float f32x4;

#define GLOAD16(gp, lp) __builtin_amdgcn_global_load_lds( \
    (const __attribute__((address_space(1))) void*)(gp),  \
    (__attribute__((address_space(3))) void*)(lp), 16, 0, 0)

__device__ __forceinline__ unsigned short f2bf(float f) {
  union { float f; unsigned u; } a; a.f = f;
  unsigned u = a.u + 0x7FFFu + ((a.u >> 16) & 1u);   // RNE
  return (unsigned short)(u >> 16);
}
__device__ __forceinline__ float bf2f(unsigned short h) {
  union { float f; unsigned u; } a; a.u = ((unsigned)h) << 16;
  return a.f;
}

// ---------------- split x into bf16 hi/lo ----------------
__global__ void split_x_kernel(const float* __restrict__ x, unsigned short* __restrict__ hi,
                               unsigned short* __restrict__ lo, int n) {
  int i = blockIdx.x * blockDim.x + threadIdx.x;
  int stride = gridDim.x * blockDim.x;
  for (; i < n; i += stride) {
    float f = x[i];
    unsigned short hb = f2bf(f);
    hi[i] = hb;
    lo[i] = f2bf(f - bf2f(hb));
  }
}

// ---------------- transpose (K,N) fp32 -> (N,K) bf16 hi (+lo) ----------------
__global__ void transpose_split_kernel(const float* __restrict__ in, unsigned short* __restrict__ hi,
                                       unsigned short* __restrict__ lo, int K, int N) {
  __shared__ float tile[32][33];
  int k0 = blockIdx.x * 32, n0 = blockIdx.y * 32;
  int tx = threadIdx.x, ty = threadIdx.y;
#pragma unroll
  for (int i = 0; i < 32; i += 8)
    tile[ty + i][tx] = in[(size_t)(k0 + ty + i) * N + n0 + tx];
  __syncthreads();
#pragma unroll
  for (int i = 0; i < 32; i += 8) {
    float f = tile[tx][ty + i];
    size_t o = (size_t)(n0 + ty + i) * K + k0 + tx;
    unsigned short hb = f2bf(f);
    hi[o] = hb;
    if (lo) lo[o] = f2bf(f - bf2f(hb));
  }
}

// ---------------- fused QKV GEMM + RoPE/split epilogue ----------------
// grid (32, 24): bn<16 -> q head bn (3-term, rope->qhi/qlo)
//                16<=bn<20 -> k head bn-16 (3-term, rope->khi/klo)
//                bn>=20 -> v head bn-20 (1-term, plain bf16 -> vun (b,g,t,d))
__global__ __launch_bounds__(256) void qkv_gemm_kernel(
    const unsigned short* __restrict__ xhi, const unsigned short* __restrict__ xlo,
    const unsigned short* __restrict__ WqThi, const unsigned short* __restrict__ WqTlo,
    const unsigned short* __restrict__ WkThi, const unsigned short* __restrict__ WkTlo,
    const unsigned short* __restrict__ WvThi,
    const float* __restrict__ cs, const float* __restrict__ sn,
    unsigned short* __restrict__ qhi, unsigned short* __restrict__ qlo,
    unsigned short* __restrict__ khi, unsigned short* __restrict__ klo,
    unsigned short* __restrict__ vun)
{
  __shared__ alignas(16) unsigned short sAh[128 * 32];
  __shared__ alignas(16) unsigned short sAl[128 * 32];
  __shared__ alignas(16) unsigned short sBh[128 * 32];
  __shared__ alignas(16) unsigned short sBl[128 * 32];
  const int K = 2048;
  int tid = threadIdx.x;
  int wid = tid >> 6, lane = tid & 63;
  int bm = blockIdx.x, bn = blockIdx.y;
  int wr = wid >> 1, wc = wid & 1;
  int ln15 = lane & 15, j8 = (lane >> 4) * 8;
  int srow = lane >> 2;
  int scol = (lane & 3) * 8;
  bool three = bn < 20;

  const unsigned short *Bh, *Bl = WqTlo;
  int brow;
  if (bn < 16)      { Bh = WqThi; Bl = WqTlo; brow = bn * 128; }
  else if (bn < 20) { Bh = WkThi; Bl = WkTlo; brow = (bn - 16) * 128; }
  else              { Bh = WvThi;             brow = (bn - 20) * 128; }

  f32x4 acc[4][4];
#pragma unroll
  for (int m = 0; m < 4; ++m)
#pragma unroll
    for (int n = 0; n < 4; ++n)
      acc[m][n] = f32x4{0.f, 0.f, 0.f, 0.f};

  const unsigned short* a0 = xhi + (size_t)(bm * 128 + wid * 32 + srow) * K + scol;
  const unsigned short* a1 = xlo + (size_t)(bm * 128 + wid * 32 + srow) * K + scol;
  const unsigned short* b0 = Bh + (size_t)(brow + wid * 32 + srow) * K + scol;
  const unsigned short* b1 = Bl + (size_t)(brow + wid * 32 + srow) * K + scol;
  unsigned short* sAhw = sAh + wid * 32 * 32;
  unsigned short* sAlw = sAl + wid * 32 * 32;
  unsigned short* sBhw = sBh + wid * 32 * 32;
  unsigned short* sBlw = sBl + wid * 32 * 32;

  int nk = K >> 5;
  if (three) {
    for (int kt = 0; kt < nk; ++kt) {
      const unsigned short* ak = a0 + kt * 32;
      const unsigned short* alk = a1 + kt * 32;
      const unsigned short* bk = b0 + kt * 32;
      const unsigned short* blk = b1 + kt * 32;
      GLOAD16(ak,          sAhw);
      GLOAD16(ak + 16 * K, sAhw + 16 * 32);
      GLOAD16(alk,          sAlw);
      GLOAD16(alk + 16 * K, sAlw + 16 * 32);
      GLOAD16(bk,          sBhw);
      GLOAD16(bk + 16 * K, sBhw + 16 * 32);
      GLOAD16(blk,          sBlw);
      GLOAD16(blk + 16 * K, sBlw + 16 * 32);
      __syncthreads();
      bf16x8 afh[4], afl[4], bfh[4], bfl[4];
#pragma unroll
      for (int m = 0; m < 4; ++m) {
        afh[m] = *(const bf16x8*)&sAh[(wr * 64 + m * 16 + ln15) * 32 + j8];
        afl[m] = *(const bf16x8*)&sAl[(wr * 64 + m * 16 + ln15) * 32 + j8];
      }
#pragma unroll
      for (int n = 0; n < 4; ++n) {
        bfh[n] = *(const bf16x8*)&sBh[(wc * 64 + n * 16 + ln15) * 32 + j8];
        bfl[n] = *(const bf16x8*)&sBl[(wc * 64 + n * 16 + ln15) * 32 + j8];
      }
      __builtin_amdgcn_s_setprio(1);
#pragma unroll
      for (int m = 0; m < 4; ++m)
#pragma unroll
        for (int n = 0; n < 4; ++n) {
          acc[m][n] = __builtin_amdgcn_mfma_f32_16x16x32_bf16(afh[m], bfh[n], acc[m][n], 0, 0, 0);
          acc[m][n] = __builtin_amdgcn_mfma_f32_16x16x32_bf16(afl[m], bfh[n], acc[m][n], 0, 0, 0);
          acc[m][n] = __builtin_amdgcn_mfma_f32_16x16x32_bf16(afh[m], bfl[n], acc[m][n], 0, 0, 0);
        }
      __builtin_amdgcn_s_setprio(0);
      __syncthreads();
    }
  } else {
    for (int kt = 0; kt < nk; ++kt) {
      const unsigned short* ak = a0 + kt * 32;
      const unsigned short* bk = b0 + kt * 32;
      GLOAD16(ak,          sAhw);
      GLOAD16(ak + 16 * K, sAhw + 16 * 32);
      GLOAD16(bk,          sBhw);
      GLOAD16(bk + 16 * K, sBhw + 16 * 32);
      __syncthreads();
      bf16x8 afh[4], bfh[4];
#pragma unroll
      for (int m = 0; m < 4; ++m)
        afh[m] = *(const bf16x8*)&sAh[(wr * 64 + m * 16 + ln15) * 32 + j8];
#pragma unroll
      for (int n = 0; n < 4; ++n)
        bfh[n] = *(const bf16x8*)&sBh[(wc * 64 + n * 16 + ln15) * 32 + j8];
      __builtin_amdgcn_s_setprio(1);
#pragma unroll
      for (int m = 0; m < 4; ++m)
#pragma unroll
        for (int n = 0; n < 4; ++n)
          acc[m][n] = __builtin_amdgcn_mfma_f32_16x16x32_bf16(afh[m], bfh[n], acc[m][n], 0, 0, 0);
      __builtin_amdgcn_s_setprio(0);
      __syncthreads();
    }
  }

  int orow0 = bm * 128 + wr * 64 + (lane >> 4) * 4;
  if (bn < 20) {
    // RoPE + split epilogue. d = wc*64 + n*16 + ln15; partner d+-32 is acc[m][n+-2].
    int nh = (bn < 16) ? Hdim : HKVdim;
    int h  = (bn < 16) ? bn : bn - 16;
    unsigned short* oph = (bn < 16) ? qhi : khi;
    unsigned short* opl = (bn < 16) ? qlo : klo;
#pragma unroll
    for (int m = 0; m < 4; ++m)
#pragma unroll
      for (int r = 0; r < 4; ++r) {
        int row = orow0 + m * 16 + r;
        int t = row & (Tdim - 1), b = row >> 11;
        size_t obase = (((size_t)(b * nh + h)) * Tdim + t) * 128;
#pragma unroll
        for (int n = 0; n < 4; ++n) {
          int d = wc * 64 + n * 16 + ln15;
          float o;
          if (wc == 0) {
            float c = cs[t * 64 + d], s = sn[t * 64 + d];
            o = (n < 2) ? (acc[m][n][r] * c - acc[m][n + 2][r] * s)
                        : (acc[m][n][r] * c + acc[m][n - 2][r] * s);
          } else o = acc[m][n][r];
          unsigned short hb = f2bf(o);
          oph[obase + d] = hb;
          opl[obase + d] = f2bf(o - bf2f(hb));
        }
      }
  } else {
    int g = bn - 20;
#pragma unroll
    for (int m = 0; m < 4; ++m)
#pragma unroll
      for (int r = 0; r < 4; ++r) {
        int row = orow0 + m * 16 + r;
        int t = row & (Tdim - 1), b = row >> 11;
        size_t obase = (((size_t)(b * HKVdim + g)) * Tdim + t) * 128;
#pragma unroll
        for (int n = 0; n < 4; ++n)
          vun[obase + wc * 64 + n * 16 + ln15] = f2bf(acc[m][n][r]);
      }
  }
}

// ---------------- Wo GEMM: out(M,2048) = yb(M,2048) @ WoT^T, fp32 out ----------------
__global__ __launch_bounds__(256) void gemm_wo_kernel(
    const unsigned short* __restrict__ A, const unsigned short* __restrict__ Bt,
    float* __restrict__ C)
{
  __shared__ alignas(16) unsigned short sA[128 * 32];
  __shared__ alignas(16) unsigned short sB[128 * 32];
  const int K = 2048, ldc = 2048;
  int tid = threadIdx.x;
  int wid = tid >> 6, lane = tid & 63;
  int bm = blockIdx.x, bn = blockIdx.y;
  int wr = wid >> 1, wc = wid & 1;
  int ln15 = lane & 15, j8 = (lane >> 4) * 8;
  int srow = lane >> 2, scol = (lane & 3) * 8;

  f32x4 acc[4][4];
#pragma unroll
  for (int m = 0; m < 4; ++m)
#pragma unroll
    for (int n = 0; n < 4; ++n)
      acc[m][n] = f32x4{0.f, 0.f, 0.f, 0.f};

  const unsigned short* a0 = A + (size_t)(bm * 128 + wid * 32 + srow) * K + scol;
  const unsigned short* b0 = Bt + (size_t)(bn * 128 + wid * 32 + srow) * K + scol;
  unsigned short* sAw = sA + wid * 32 * 32;
  unsigned short* sBw = sB + wid * 32 * 32;

  for (int kt = 0; kt < (K >> 5); ++kt) {
    const unsigned short* ak = a0 + kt * 32;
    const unsigned short* bk = b0 + kt * 32;
    GLOAD16(ak,          sAw);
    GLOAD16(ak + 16 * K, sAw + 16 * 32);
    GLOAD16(bk,          sBw);
    GLOAD16(bk + 16 * K, sBw + 16 * 32);
    __syncthreads();
    bf16x8 af[4], bfv[4];
#pragma unroll
    for (int m = 0; m < 4; ++m)
      af[m] = *(const bf16x8*)&sA[(wr * 64 + m * 16 + ln15) * 32 + j8];
#pragma unroll
    for (int n = 0; n < 4; ++n)
      bfv[n] = *(const bf16x8*)&sB[(wc * 64 + n * 16 + ln15) * 32 + j8];
    __builtin_amdgcn_s_setprio(1);
#pragma unroll
    for (int m = 0; m < 4; ++m)
#pragma unroll
      for (int n = 0; n < 4; ++n)
        acc[m][n] = __builtin_amdgcn_mfma_f32_16x16x32_bf16(af[m], bfv[n], acc[m][n], 0, 0, 0);
    __builtin_amdgcn_s_setprio(0);
    __syncthreads();
  }

  int orow0 = bm * 128 + wr * 64 + (lane >> 4) * 4;
  int ocol0 = bn * 128 + wc * 64 + ln15;
#pragma unroll
  for (int m = 0; m < 4; ++m)
#pragma unroll
    for (int n = 0; n < 4; ++n)
#pragma unroll
      for (int r = 0; r < 4; ++r)
        C[(size_t)(orow0 + m * 16 + r) * ldc + ocol0 + n * 16] = acc[m][n][r];
}

// ---------------- v transpose: (b,g,t,d) bf16 -> (b,g,d,t) bf16 ----------------
__global__ void transpose_v_bf16_kernel(const unsigned short* __restrict__ vsrc,
                                        unsigned short* __restrict__ vt) {
  __shared__ unsigned short tile[32][33];
  int bg = blockIdx.x;
  int t0 = blockIdx.y * 32, d0 = blockIdx.z * 32;
  int tx = threadIdx.x, ty = threadIdx.y;
#pragma unroll
  for (int i = 0; i < 32; i += 8)
    tile[ty + i][tx] = vsrc[((size_t)bg * Tdim + t0 + ty + i) * 128 + d0 + tx];
  __syncthreads();
#pragma unroll
  for (int i = 0; i < 32; i += 8)
    vt[((size_t)(bg * 128 + d0 + ty + i)) * Tdim + t0 + tx] = tile[tx][ty + i];
}

// ---------------- fused causal GQA attention with post-softmax gate ----------------
// Fixed-M softmax (M=8, exp2 with folded scale*log2e): l = sum 2^(s2-M2) is exact for
// any fixed M; no online max tracking. Two-pass, pass-B block skip via pass-A block max.
__global__ __launch_bounds__(512, 4) void attn_kernel(
    const unsigned short* __restrict__ qhi, const unsigned short* __restrict__ qlo,
    const unsigned short* __restrict__ khi, const unsigned short* __restrict__ klo,
    const unsigned short* __restrict__ vt, const float* __restrict__ gate,
    unsigned short* __restrict__ y)
{
  __shared__ alignas(16) unsigned short sKh[2][KT * 128];
  __shared__ alignas(16) unsigned short sKl[2][KT * 128];
  __shared__ alignas(16) unsigned short sV[2][128 * KT];
  __shared__ alignas(16) unsigned short sP[8][16 * 40];
  __shared__ float sBM[8][64];

  int qb = (gridDim.x - 1) - blockIdx.x;     // heavy blocks first
  int bh = blockIdx.y;
  int b = bh >> 4, h = bh & 15;
  int g = h >> 2;
  int t0 = qb * 128;
  int tid = threadIdx.x, wid = tid >> 6, lane = tid & 63;
  int ln15 = lane & 15, j16 = (lane >> 4) * 16, ro4 = (lane >> 4) * 4;
  const float cs2 = 0.08838834764831845f * 1.4426950408889634f;  // scale*log2(e)
  const float M2  = 8.0f * 1.4426950408889634f;

  const unsigned short* kh_base = khi + (((size_t)b * HKVdim + g) * Tdim) * 128;
  const unsigned short* kl_base = klo + (((size_t)b * HKVdim + g) * Tdim) * 128;
  const unsigned short* v_base  = vt  + (((size_t)b * HKVdim + g) * 128) * (size_t)Tdim;

  bf16x8 aqh[4], aql[4];
  {
    size_t qoff = ((((size_t)b * Hdim + h) * Tdim) + t0 + wid * 16 + ln15) * 128 + (lane >> 4) * 8;
#pragma unroll
    for (int kf = 0; kf < 4; ++kf) {
      aqh[kf] = *(const bf16x8*)(qhi + qoff + kf * 32);
      aql[kf] = *(const bf16x8*)(qlo + qoff + kf * 32);
    }
  }
  float thr = 1.f / (1.f + expf(-gate[h]));

  int nkb = (qb + 1) * 4;
  int tq_lo = t0 + wid * 16;

  auto stageK = [&](int buf, int kb) {
    int o = wid * 1024 + lane * 16;
    int row = o >> 8;
    int col = (o & 255) ^ ((row & 7) << 4);
    size_t goff = ((size_t)(kb * KT + row)) * 256 + col;
    GLOAD16((const char*)kh_base + goff, (char*)sKh[buf] + wid * 1024);
    GLOAD16((const char*)kl_base + goff, (char*)sKl[buf] + wid * 1024);
  };
  auto stageV = [&](int buf, int kb) {
    int o = wid * 1024 + lane * 16;
    int row = o >> 6;
    int col = (o & 63) ^ (((row ^ (row >> 2)) & 3) << 4);
    size_t goff = (size_t)row * (Tdim * 2) + (size_t)kb * 64 + col;
    GLOAD16((const char*)v_base + goff, (char*)sV[buf] + wid * 1024);
  };
  auto qk = [&](int buf, f32x4* s) {
    __builtin_amdgcn_s_setprio(1);
#pragma unroll
    for (int nf = 0; nf < 2; ++nf) {
      f32x4 a = {0.f, 0.f, 0.f, 0.f};
      int krow = nf * 16 + ln15;
      int sw = (krow & 7) << 4;
#pragma unroll
      for (int kf = 0; kf < 4; ++kf) {
        int boff = (kf * 64 + j16) ^ sw;
        bf16x8 bh_ = *(const bf16x8*)((const char*)sKh[buf] + krow * 256 + boff);
        bf16x8 bl_ = *(const bf16x8*)((const char*)sKl[buf] + krow * 256 + boff);
        a = __builtin_amdgcn_mfma_f32_16x16x32_bf16(aqh[kf], bh_, a, 0, 0, 0);
        a = __builtin_amdgcn_mfma_f32_16x16x32_bf16(aql[kf], bh_, a, 0, 0, 0);
        a = __builtin_amdgcn_mfma_f32_16x16x32_bf16(aqh[kf], bl_, a, 0, 0, 0);
      }
      s[nf] = a;
    }
    __builtin_amdgcn_s_setprio(0);
  };

  float lloc[4];
#pragma unroll
  for (int r = 0; r < 4; ++r) lloc[r] = 0.f;

  // ---- PASS A: l = sum 2^(s2-M2); per-block wave max for pass-B skip ----
  stageK(0, 0);
  __syncthreads();
  for (int kb = 0; kb < nkb; ++kb) {
    int buf = kb & 1;
    if (kb + 1 < nkb) stageK(buf ^ 1, kb + 1);
    if (kb * KT <= tq_lo + 15) {
      f32x4 s[2];
      qk(buf, s);
      float wmax = -1e30f;
      bool full = (kb * KT + KT - 1) <= tq_lo;   // wave-uniform: no masked entries
      if (full) {
#pragma unroll
        for (int nf = 0; nf < 2; ++nf)
#pragma unroll
          for (int r = 0; r < 4; ++r) {
            float v = s[nf][r] * cs2;
            wmax = fmaxf(wmax, v);
            lloc[r] += __builtin_exp2f(v - M2);
          }
      } else {
#pragma unroll
        for (int nf = 0; nf < 2; ++nf) {
          int tk = kb * KT + nf * 16 + ln15;
#pragma unroll
          for (int r = 0; r < 4; ++r) {
            int tq = tq_lo + ro4 + r;
            float v = (tk <= tq) ? s[nf][r] * cs2 : -1e30f;
            wmax = fmaxf(wmax, v);
            lloc[r] += __builtin_exp2f(v - M2);   // exp2(-1e30) == 0
          }
        }
      }
#pragma unroll
      for (int off = 1; off < 64; off <<= 1)
        wmax = fmaxf(wmax, __shfl_xor(wmax, off));
      if (lane == 0) sBM[wid][kb] = wmax;
    }
    __syncthreads();
  }

  // merge l across the 16 k-residue lanes (bits 0-3); build log2-space gate
  float lrow[4], lgate2[4];
#pragma unroll
  for (int r = 0; r < 4; ++r) {
    float l = lloc[r];
#pragma unroll
    for (int off = 1; off < 16; off <<= 1) l += __shfl_xor(l, off);
    lrow[r] = l;
    lgate2[r] = __log2f(thr * l) + M2;           // keep iff s2 >= lgate2
  }
  float lgmin = fminf(fminf(lgate2[0], lgate2[1]), fminf(lgate2[2], lgate2[3]));
  lgmin = fminf(lgmin, __shfl_xor(lgmin, 16));
  lgmin = fminf(lgmin, __shfl_xor(lgmin, 32));

  // ---- PASS B: QK only on live blocks, gate, PV ----
  f32x4 yacc[8];
#pragma unroll
  for (int n = 0; n < 8; ++n) yacc[n] = f32x4{0.f, 0.f, 0.f, 0.f};

  stageK(0, 0);
  stageV(0, 0);
  __syncthreads();
  for (int kb = 0; kb < nkb; ++kb) {
    int buf = kb & 1;
    if (kb + 1 < nkb) { stageK(buf ^ 1, kb + 1); stageV(buf ^ 1, kb + 1); }
    if (kb * KT <= tq_lo + 15 && sBM[wid][kb] >= lgmin) {
      f32x4 s[2];
      qk(buf, s);
      bool anyk = false;
      float pv[2][4];
      bool full = (kb * KT + KT - 1) <= tq_lo;
#pragma unroll
      for (int nf = 0; nf < 2; ++nf) {
        int tk = kb * KT + nf * 16 + ln15;
#pragma unroll
        for (int r = 0; r < 4; ++r) {
          int tq = tq_lo + ro4 + r;
          float v = s[nf][r] * cs2;
          bool keep = (full || tk <= tq) && (v >= lgate2[r]);
          float p = 0.f;
          if (keep) { p = __builtin_exp2f(v - M2); anyk = true; }
          pv[nf][r] = p;
        }
      }
      if (__any(anyk)) {
#pragma unroll
        for (int nf = 0; nf < 2; ++nf)
#pragma unroll
          for (int r = 0; r < 4; ++r)
            sP[wid][(ro4 + r) * 40 + nf * 16 + ln15] = f2bf(pv[nf][r]);
        __builtin_amdgcn_s_setprio(1);
        bf16x8 pa = *(const bf16x8*)&sP[wid][ln15 * 40 + (lane >> 4) * 8];
#pragma unroll
        for (int nf2 = 0; nf2 < 8; ++nf2) {
          int vrow = nf2 * 16 + ln15;
          int vboff = j16 ^ (((vrow ^ (vrow >> 2)) & 3) << 4);
          bf16x8 vb = *(const bf16x8*)((const char*)sV[buf] + vrow * 64 + vboff);
          yacc[nf2] = __builtin_amdgcn_mfma_f32_16x16x32_bf16(pa, vb, yacc[nf2], 0, 0, 0);
        }
        __builtin_amdgcn_s_setprio(0);
      }
    }
    __syncthreads();
  }

  // epilogue: y (b,t,h,d) bf16
#pragma unroll
  for (int r = 0; r < 4; ++r) {
    int tq = t0 + wid * 16 + ro4 + r;
    float invl = 1.f / lrow[r];
    size_t base = ((size_t)(b * Tdim + tq)) * Cdim + h * 128;
#pragma unroll
    for (int nf2 = 0; nf2 < 8; ++nf2)
      y[base + nf2 * 16 + ln15] = f2bf(yacc[nf2][r] * invl);
  }
}

extern "C" void kernel_launch(void* const* d_in, const int* in_sizes, int n_in,
                              void* d_out, int out_size, void* d_ws, size_t ws_size,
                              hipStream_t stream)
{
  (void)in_sizes; (void)n_in; (void)out_size; (void)ws_size;
  const float* x    = (const float*)d_in[0];
  const float* cosT = (const float*)d_in[1];
  const float* sinT = (const float*)d_in[2];
  const float* Wq   = (const float*)d_in[3];
  const float* Wk   = (const float*)d_in[4];
  const float* Wv   = (const float*)d_in[5];
  const float* Wo   = (const float*)d_in[6];
  const float* gate = (const float*)d_in[7];
  float* out = (float*)d_out;

  char* ws = (char*)d_ws;
  size_t off = 0;
  auto alloc = [&](size_t bytes) -> char* {
    char* p = ws + off; off += (bytes + 255) & ~(size_t)255; return p;
  };
  const size_t NX = (size_t)Bdim * Tdim * Cdim;    // 8388608
  const size_t NK = (size_t)Bdim * Tdim * KVdim;   // 2097152

  unsigned short* xhi   = (unsigned short*)alloc(NX * 2);
  unsigned short* xlo   = (unsigned short*)alloc(NX * 2);
  unsigned short* WqThi = (unsigned short*)alloc((size_t)Cdim * Cdim * 2);
  unsigned short* WqTlo = (unsigned short*)alloc((size_t)Cdim * Cdim * 2);
  unsigned short* WkThi = (unsigned short*)alloc((size_t)Cdim * KVdim * 2);
  unsigned short* WkTlo = (unsigned short*)alloc((size_t)Cdim * KVdim * 2);
  unsigned short* WvThi = (unsigned short*)alloc((size_t)Cdim * KVdim * 2);
  unsigned short* WoThi = (unsigned short*)alloc((size_t)Cdim * Cdim * 2);
  unsigned short* qhi   = (unsigned short*)alloc(NX * 2);
  unsigned short* qlo   = (unsigned short*)alloc(NX * 2);
  unsigned short* khi   = (unsigned short*)alloc(NK * 2);
  unsigned short* klo   = (unsigned short*)alloc(NK * 2);
  unsigned short* vun   = (unsigned short*)alloc(NK * 2);
  unsigned short* vtr   = (unsigned short*)alloc(NK * 2);
  unsigned short* yb    = (unsigned short*)alloc(NX * 2);

  dim3 tb(32, 8);
  split_x_kernel<<<2048, 256, 0, stream>>>(x, xhi, xlo, (int)NX);
  transpose_split_kernel<<<dim3(64, 64), tb, 0, stream>>>(Wq, WqThi, WqTlo, Cdim, Cdim);
  transpose_split_kernel<<<dim3(64, 16), tb, 0, stream>>>(Wk, WkThi, WkTlo, Cdim, KVdim);
  transpose_split_kernel<<<dim3(64, 16), tb, 0, stream>>>(Wv, WvThi, nullptr, Cdim, KVdim);
  transpose_split_kernel<<<dim3(64, 64), tb, 0, stream>>>(Wo, WoThi, nullptr, Cdim, Cdim);

  // q, k (split-3, rope+split fused) and v (1-term) in one dispatch
  qkv_gemm_kernel<<<dim3(32, 24), 256, 0, stream>>>(
      xhi, xlo, WqThi, WqTlo, WkThi, WkTlo, WvThi,
      cosT, sinT, qhi, qlo, khi, klo, vun);
  transpose_v_bf16_kernel<<<dim3(8, 64, 4), tb, 0, stream>>>(vun, vtr);

  attn_kernel<<<dim3(16, 32), 512, 0, stream>>>(qhi, qlo, khi, klo, vtr, gate, yb);

  gemm_wo_kernel<<<dim3(32, 16), 256, 0, stream>>>(yb, WoThi, out);
}

// Round 6
// 404.374 us; speedup vs baseline: 2.2139x; 1.1353x over previous
//
#include <hip/hip_runtime.h>
#include <stdint.h>

#define Bdim 2
#define Tdim 2048
#define Cdim 2048
#define Hdim 16
#define HKVdim 4
#define KVdim 512   // HKV*D
#define KT 32       // attn k-tile rows

typedef __attribute__((ext_vector_type(8))) short bf16x8;
typedef __attribute__((ext_vector_type(4))) float f32x4;

#define GLOAD16(gp, lp) __builtin_amdgcn_global_load_lds( \
    (const __attribute__((address_space(1))) void*)(gp),  \
    (__attribute__((address_space(3))) void*)(lp), 16, 0, 0)

__device__ __forceinline__ unsigned short f2bf(float f) {
  union { float f; unsigned u; } a; a.f = f;
  unsigned u = a.u + 0x7FFFu + ((a.u >> 16) & 1u);   // RNE
  return (unsigned short)(u >> 16);
}
__device__ __forceinline__ float bf2f(unsigned short h) {
  union { float f; unsigned u; } a; a.u = ((unsigned)h) << 16;
  return a.f;
}

// ---------------- split x into bf16 hi/lo ----------------
__global__ void split_x_kernel(const float* __restrict__ x, unsigned short* __restrict__ hi,
                               unsigned short* __restrict__ lo, int n) {
  int i = blockIdx.x * blockDim.x + threadIdx.x;
  int stride = gridDim.x * blockDim.x;
  for (; i < n; i += stride) {
    float f = x[i];
    unsigned short hb = f2bf(f);
    hi[i] = hb;
    lo[i] = f2bf(f - bf2f(hb));
  }
}

// ---------------- transpose (K,N) fp32 -> (N,K) bf16 hi (+lo) ----------------
__global__ void transpose_split_kernel(const float* __restrict__ in, unsigned short* __restrict__ hi,
                                       unsigned short* __restrict__ lo, int K, int N) {
  __shared__ float tile[32][33];
  int k0 = blockIdx.x * 32, n0 = blockIdx.y * 32;
  int tx = threadIdx.x, ty = threadIdx.y;
#pragma unroll
  for (int i = 0; i < 32; i += 8)
    tile[ty + i][tx] = in[(size_t)(k0 + ty + i) * N + n0 + tx];
  __syncthreads();
#pragma unroll
  for (int i = 0; i < 32; i += 8) {
    float f = tile[tx][ty + i];
    size_t o = (size_t)(n0 + ty + i) * K + k0 + tx;
    unsigned short hb = f2bf(f);
    hi[o] = hb;
    if (lo) lo[o] = f2bf(f - bf2f(hb));
  }
}

// ---------------- fused QKV GEMM + RoPE/split epilogue, 2-phase dbuf pipeline ------
// grid (32, 24): bn<16 -> q head bn (3-term, rope->qhi/qlo)
//                16<=bn<20 -> k head bn-16 (3-term, rope->khi/klo)
//                bn>=20 -> v head bn-20 (1-term, plain bf16 -> vun (b,g,t,d))
__global__ __launch_bounds__(256) void qkv_gemm_kernel(
    const unsigned short* __restrict__ xhi, const unsigned short* __restrict__ xlo,
    const unsigned short* __restrict__ WqThi, const unsigned short* __restrict__ WqTlo,
    const unsigned short* __restrict__ WkThi, const unsigned short* __restrict__ WkTlo,
    const unsigned short* __restrict__ WvThi,
    const float* __restrict__ cs, const float* __restrict__ sn,
    unsigned short* __restrict__ qhi, unsigned short* __restrict__ qlo,
    unsigned short* __restrict__ khi, unsigned short* __restrict__ klo,
    unsigned short* __restrict__ vun)
{
  __shared__ alignas(16) unsigned short sAh[2][128 * 32];
  __shared__ alignas(16) unsigned short sAl[2][128 * 32];
  __shared__ alignas(16) unsigned short sBh[2][128 * 32];
  __shared__ alignas(16) unsigned short sBl[2][128 * 32];
  const int K = 2048;
  int tid = threadIdx.x;
  int wid = tid >> 6, lane = tid & 63;
  int bm = blockIdx.x, bn = blockIdx.y;
  int wr = wid >> 1, wc = wid & 1;
  int ln15 = lane & 15, j8 = (lane >> 4) * 8;
  int srow = lane >> 2;
  int scol = (lane & 3) * 8;
  bool three = bn < 20;

  const unsigned short *Bh, *Bl = WqTlo;
  int brow;
  if (bn < 16)      { Bh = WqThi; Bl = WqTlo; brow = bn * 128; }
  else if (bn < 20) { Bh = WkThi; Bl = WkTlo; brow = (bn - 16) * 128; }
  else              { Bh = WvThi;             brow = (bn - 20) * 128; }

  f32x4 acc[4][4];
#pragma unroll
  for (int m = 0; m < 4; ++m)
#pragma unroll
    for (int n = 0; n < 4; ++n)
      acc[m][n] = f32x4{0.f, 0.f, 0.f, 0.f};

  const unsigned short* a0 = xhi + (size_t)(bm * 128 + wid * 32 + srow) * K + scol;
  const unsigned short* a1 = xlo + (size_t)(bm * 128 + wid * 32 + srow) * K + scol;
  const unsigned short* b0 = Bh + (size_t)(brow + wid * 32 + srow) * K + scol;
  const unsigned short* b1 = Bl + (size_t)(brow + wid * 32 + srow) * K + scol;
  int wlds = wid * 32 * 32;

  int nk = K >> 5;
  if (three) {
    auto stage3 = [&](int buf, int kt) {
      const unsigned short* ak = a0 + kt * 32;
      const unsigned short* alk = a1 + kt * 32;
      const unsigned short* bk = b0 + kt * 32;
      const unsigned short* blk = b1 + kt * 32;
      GLOAD16(ak,          &sAh[buf][wlds]);
      GLOAD16(ak + 16 * K, &sAh[buf][wlds + 16 * 32]);
      GLOAD16(alk,          &sAl[buf][wlds]);
      GLOAD16(alk + 16 * K, &sAl[buf][wlds + 16 * 32]);
      GLOAD16(bk,          &sBh[buf][wlds]);
      GLOAD16(bk + 16 * K, &sBh[buf][wlds + 16 * 32]);
      GLOAD16(blk,          &sBl[buf][wlds]);
      GLOAD16(blk + 16 * K, &sBl[buf][wlds + 16 * 32]);
    };
    stage3(0, 0);
    __syncthreads();
    int buf = 0;
    for (int kt = 0; kt < nk; ++kt) {
      bf16x8 afh[4], afl[4], bfh[4], bfl[4];
#pragma unroll
      for (int m = 0; m < 4; ++m) {
        afh[m] = *(const bf16x8*)&sAh[buf][(wr * 64 + m * 16 + ln15) * 32 + j8];
        afl[m] = *(const bf16x8*)&sAl[buf][(wr * 64 + m * 16 + ln15) * 32 + j8];
      }
#pragma unroll
      for (int n = 0; n < 4; ++n) {
        bfh[n] = *(const bf16x8*)&sBh[buf][(wc * 64 + n * 16 + ln15) * 32 + j8];
        bfl[n] = *(const bf16x8*)&sBl[buf][(wc * 64 + n * 16 + ln15) * 32 + j8];
      }
      if (kt + 1 < nk) stage3(buf ^ 1, kt + 1);   // in flight during MFMAs
      __builtin_amdgcn_s_setprio(1);
#pragma unroll
      for (int m = 0; m < 4; ++m)
#pragma unroll
        for (int n = 0; n < 4; ++n)
          acc[m][n] = __builtin_amdgcn_mfma_f32_16x16x32_bf16(afh[m], bfh[n], acc[m][n], 0, 0, 0);
#pragma unroll
      for (int m = 0; m < 4; ++m)
#pragma unroll
        for (int n = 0; n < 4; ++n)
          acc[m][n] = __builtin_amdgcn_mfma_f32_16x16x32_bf16(afl[m], bfh[n], acc[m][n], 0, 0, 0);
#pragma unroll
      for (int m = 0; m < 4; ++m)
#pragma unroll
        for (int n = 0; n < 4; ++n)
          acc[m][n] = __builtin_amdgcn_mfma_f32_16x16x32_bf16(afh[m], bfl[n], acc[m][n], 0, 0, 0);
      __builtin_amdgcn_s_setprio(0);
      __syncthreads();                            // drains vmcnt; next buf ready
      buf ^= 1;
    }
  } else {
    auto stage1 = [&](int buf, int kt) {
      const unsigned short* ak = a0 + kt * 32;
      const unsigned short* bk = b0 + kt * 32;
      GLOAD16(ak,          &sAh[buf][wlds]);
      GLOAD16(ak + 16 * K, &sAh[buf][wlds + 16 * 32]);
      GLOAD16(bk,          &sBh[buf][wlds]);
      GLOAD16(bk + 16 * K, &sBh[buf][wlds + 16 * 32]);
    };
    stage1(0, 0);
    __syncthreads();
    int buf = 0;
    for (int kt = 0; kt < nk; ++kt) {
      bf16x8 afh[4], bfh[4];
#pragma unroll
      for (int m = 0; m < 4; ++m)
        afh[m] = *(const bf16x8*)&sAh[buf][(wr * 64 + m * 16 + ln15) * 32 + j8];
#pragma unroll
      for (int n = 0; n < 4; ++n)
        bfh[n] = *(const bf16x8*)&sBh[buf][(wc * 64 + n * 16 + ln15) * 32 + j8];
      if (kt + 1 < nk) stage1(buf ^ 1, kt + 1);
      __builtin_amdgcn_s_setprio(1);
#pragma unroll
      for (int m = 0; m < 4; ++m)
#pragma unroll
        for (int n = 0; n < 4; ++n)
          acc[m][n] = __builtin_amdgcn_mfma_f32_16x16x32_bf16(afh[m], bfh[n], acc[m][n], 0, 0, 0);
      __builtin_amdgcn_s_setprio(0);
      __syncthreads();
      buf ^= 1;
    }
  }

  int orow0 = bm * 128 + wr * 64 + (lane >> 4) * 4;
  if (bn < 20) {
    // RoPE + split epilogue. d = wc*64 + n*16 + ln15; partner d+-32 is acc[m][n+-2].
    int nh = (bn < 16) ? Hdim : HKVdim;
    int h  = (bn < 16) ? bn : bn - 16;
    unsigned short* oph = (bn < 16) ? qhi : khi;
    unsigned short* opl = (bn < 16) ? qlo : klo;
#pragma unroll
    for (int m = 0; m < 4; ++m)
#pragma unroll
      for (int r = 0; r < 4; ++r) {
        int row = orow0 + m * 16 + r;
        int t = row & (Tdim - 1), b = row >> 11;
        size_t obase = (((size_t)(b * nh + h)) * Tdim + t) * 128;
#pragma unroll
        for (int n = 0; n < 4; ++n) {
          int d = wc * 64 + n * 16 + ln15;
          float o;
          if (wc == 0) {
            float c = cs[t * 64 + d], s = sn[t * 64 + d];
            o = (n < 2) ? (acc[m][n][r] * c - acc[m][n + 2][r] * s)
                        : (acc[m][n][r] * c + acc[m][n - 2][r] * s);
          } else o = acc[m][n][r];
          unsigned short hb = f2bf(o);
          oph[obase + d] = hb;
          opl[obase + d] = f2bf(o - bf2f(hb));
        }
      }
  } else {
    int g = bn - 20;
#pragma unroll
    for (int m = 0; m < 4; ++m)
#pragma unroll
      for (int r = 0; r < 4; ++r) {
        int row = orow0 + m * 16 + r;
        int t = row & (Tdim - 1), b = row >> 11;
        size_t obase = (((size_t)(b * HKVdim + g)) * Tdim + t) * 128;
#pragma unroll
        for (int n = 0; n < 4; ++n)
          vun[obase + wc * 64 + n * 16 + ln15] = f2bf(acc[m][n][r]);
      }
  }
}

// ---------------- Wo GEMM: out(M,2048) = yb(M,2048) @ WoT^T, fp32 out, dbuf ----------
__global__ __launch_bounds__(256) void gemm_wo_kernel(
    const unsigned short* __restrict__ A, const unsigned short* __restrict__ Bt,
    float* __restrict__ C)
{
  __shared__ alignas(16) unsigned short sA[2][128 * 32];
  __shared__ alignas(16) unsigned short sB[2][128 * 32];
  const int K = 2048, ldc = 2048;
  int tid = threadIdx.x;
  int wid = tid >> 6, lane = tid & 63;
  int bm = blockIdx.x, bn = blockIdx.y;
  int wr = wid >> 1, wc = wid & 1;
  int ln15 = lane & 15, j8 = (lane >> 4) * 8;
  int srow = lane >> 2, scol = (lane & 3) * 8;

  f32x4 acc[4][4];
#pragma unroll
  for (int m = 0; m < 4; ++m)
#pragma unroll
    for (int n = 0; n < 4; ++n)
      acc[m][n] = f32x4{0.f, 0.f, 0.f, 0.f};

  const unsigned short* a0 = A + (size_t)(bm * 128 + wid * 32 + srow) * K + scol;
  const unsigned short* b0 = Bt + (size_t)(bn * 128 + wid * 32 + srow) * K + scol;
  int wlds = wid * 32 * 32;

  auto stage = [&](int buf, int kt) {
    const unsigned short* ak = a0 + kt * 32;
    const unsigned short* bk = b0 + kt * 32;
    GLOAD16(ak,          &sA[buf][wlds]);
    GLOAD16(ak + 16 * K, &sA[buf][wlds + 16 * 32]);
    GLOAD16(bk,          &sB[buf][wlds]);
    GLOAD16(bk + 16 * K, &sB[buf][wlds + 16 * 32]);
  };
  int nk = K >> 5;
  stage(0, 0);
  __syncthreads();
  int buf = 0;
  for (int kt = 0; kt < nk; ++kt) {
    bf16x8 af[4], bfv[4];
#pragma unroll
    for (int m = 0; m < 4; ++m)
      af[m] = *(const bf16x8*)&sA[buf][(wr * 64 + m * 16 + ln15) * 32 + j8];
#pragma unroll
    for (int n = 0; n < 4; ++n)
      bfv[n] = *(const bf16x8*)&sB[buf][(wc * 64 + n * 16 + ln15) * 32 + j8];
    if (kt + 1 < nk) stage(buf ^ 1, kt + 1);
    __builtin_amdgcn_s_setprio(1);
#pragma unroll
    for (int m = 0; m < 4; ++m)
#pragma unroll
      for (int n = 0; n < 4; ++n)
        acc[m][n] = __builtin_amdgcn_mfma_f32_16x16x32_bf16(af[m], bfv[n], acc[m][n], 0, 0, 0);
    __builtin_amdgcn_s_setprio(0);
    __syncthreads();
    buf ^= 1;
  }

  int orow0 = bm * 128 + wr * 64 + (lane >> 4) * 4;
  int ocol0 = bn * 128 + wc * 64 + ln15;
#pragma unroll
  for (int m = 0; m < 4; ++m)
#pragma unroll
    for (int n = 0; n < 4; ++n)
#pragma unroll
      for (int r = 0; r < 4; ++r)
        C[(size_t)(orow0 + m * 16 + r) * ldc + ocol0 + n * 16] = acc[m][n][r];
}

// ---------------- v transpose: (b,g,t,d) bf16 -> (b,g,d,t) bf16 ----------------
__global__ void transpose_v_bf16_kernel(const unsigned short* __restrict__ vsrc,
                                        unsigned short* __restrict__ vt) {
  __shared__ unsigned short tile[32][33];
  int bg = blockIdx.x;
  int t0 = blockIdx.y * 32, d0 = blockIdx.z * 32;
  int tx = threadIdx.x, ty = threadIdx.y;
#pragma unroll
  for (int i = 0; i < 32; i += 8)
    tile[ty + i][tx] = vsrc[((size_t)bg * Tdim + t0 + ty + i) * 128 + d0 + tx];
  __syncthreads();
#pragma unroll
  for (int i = 0; i < 32; i += 8)
    vt[((size_t)(bg * 128 + d0 + ty + i)) * Tdim + t0 + tx] = tile[tx][ty + i];
}

// ---------------- fused causal GQA attention with post-softmax gate ----------------
// Fixed-M softmax (M=8, exp2 with folded scale*log2e): l = sum 2^(s2-M2) is exact for
// any fixed M; no online max tracking. Two-pass, pass-B block skip via pass-A block max.
__global__ __launch_bounds__(512, 4) void attn_kernel(
    const unsigned short* __restrict__ qhi, const unsigned short* __restrict__ qlo,
    const unsigned short* __restrict__ khi, const unsigned short* __restrict__ klo,
    const unsigned short* __restrict__ vt, const float* __restrict__ gate,
    unsigned short* __restrict__ y)
{
  __shared__ alignas(16) unsigned short sKh[2][KT * 128];
  __shared__ alignas(16) unsigned short sKl[2][KT * 128];
  __shared__ alignas(16) unsigned short sV[2][128 * KT];
  __shared__ alignas(16) unsigned short sP[8][16 * 40];
  __shared__ float sBM[8][64];

  int qb = (gridDim.x - 1) - blockIdx.x;     // heavy blocks first
  int bh = blockIdx.y;
  int b = bh >> 4, h = bh & 15;
  int g = h >> 2;
  int t0 = qb * 128;
  int tid = threadIdx.x, wid = tid >> 6, lane = tid & 63;
  int ln15 = lane & 15, j16 = (lane >> 4) * 16, ro4 = (lane >> 4) * 4;
  const float cs2 = 0.08838834764831845f * 1.4426950408889634f;  // scale*log2(e)
  const float M2  = 8.0f * 1.4426950408889634f;

  const unsigned short* kh_base = khi + (((size_t)b * HKVdim + g) * Tdim) * 128;
  const unsigned short* kl_base = klo + (((size_t)b * HKVdim + g) * Tdim) * 128;
  const unsigned short* v_base  = vt  + (((size_t)b * HKVdim + g) * 128) * (size_t)Tdim;

  bf16x8 aqh[4], aql[4];
  {
    size_t qoff = ((((size_t)b * Hdim + h) * Tdim) + t0 + wid * 16 + ln15) * 128 + (lane >> 4) * 8;
#pragma unroll
    for (int kf = 0; kf < 4; ++kf) {
      aqh[kf] = *(const bf16x8*)(qhi + qoff + kf * 32);
      aql[kf] = *(const bf16x8*)(qlo + qoff + kf * 32);
    }
  }
  float thr = 1.f / (1.f + expf(-gate[h]));

  int nkb = (qb + 1) * 4;
  int tq_lo = t0 + wid * 16;

  auto stageK = [&](int buf, int kb) {
    int o = wid * 1024 + lane * 16;
    int row = o >> 8;
    int col = (o & 255) ^ ((row & 7) << 4);
    size_t goff = ((size_t)(kb * KT + row)) * 256 + col;
    GLOAD16((const char*)kh_base + goff, (char*)sKh[buf] + wid * 1024);
    GLOAD16((const char*)kl_base + goff, (char*)sKl[buf] + wid * 1024);
  };
  auto stageV = [&](int buf, int kb) {
    int o = wid * 1024 + lane * 16;
    int row = o >> 6;
    int col = (o & 63) ^ (((row ^ (row >> 2)) & 3) << 4);
    size_t goff = (size_t)row * (Tdim * 2) + (size_t)kb * 64 + col;
    GLOAD16((const char*)v_base + goff, (char*)sV[buf] + wid * 1024);
  };
  auto qk = [&](int buf, f32x4* s) {
    __builtin_amdgcn_s_setprio(1);
#pragma unroll
    for (int nf = 0; nf < 2; ++nf) {
      f32x4 a = {0.f, 0.f, 0.f, 0.f};
      int krow = nf * 16 + ln15;
      int sw = (krow & 7) << 4;
#pragma unroll
      for (int kf = 0; kf < 4; ++kf) {
        int boff = (kf * 64 + j16) ^ sw;
        bf16x8 bh_ = *(const bf16x8*)((const char*)sKh[buf] + krow * 256 + boff);
        bf16x8 bl_ = *(const bf16x8*)((const char*)sKl[buf] + krow * 256 + boff);
        a = __builtin_amdgcn_mfma_f32_16x16x32_bf16(aqh[kf], bh_, a, 0, 0, 0);
        a = __builtin_amdgcn_mfma_f32_16x16x32_bf16(aql[kf], bh_, a, 0, 0, 0);
        a = __builtin_amdgcn_mfma_f32_16x16x32_bf16(aqh[kf], bl_, a, 0, 0, 0);
      }
      s[nf] = a;
    }
    __builtin_amdgcn_s_setprio(0);
  };

  float lloc[4];
#pragma unroll
  for (int r = 0; r < 4; ++r) lloc[r] = 0.f;

  // ---- PASS A: l = sum 2^(s2-M2); per-block wave max for pass-B skip ----
  stageK(0, 0);
  __syncthreads();
  for (int kb = 0; kb < nkb; ++kb) {
    int buf = kb & 1;
    if (kb + 1 < nkb) stageK(buf ^ 1, kb + 1);
    if (kb * KT <= tq_lo + 15) {
      f32x4 s[2];
      qk(buf, s);
      float wmax = -1e30f;
      bool full = (kb * KT + KT - 1) <= tq_lo;   // wave-uniform: no masked entries
      if (full) {
#pragma unroll
        for (int nf = 0; nf < 2; ++nf)
#pragma unroll
          for (int r = 0; r < 4; ++r) {
            float v = s[nf][r] * cs2;
            wmax = fmaxf(wmax, v);
            lloc[r] += __builtin_exp2f(v - M2);
          }
      } else {
#pragma unroll
        for (int nf = 0; nf < 2; ++nf) {
          int tk = kb * KT + nf * 16 + ln15;
#pragma unroll
          for (int r = 0; r < 4; ++r) {
            int tq = tq_lo + ro4 + r;
            float v = (tk <= tq) ? s[nf][r] * cs2 : -1e30f;
            wmax = fmaxf(wmax, v);
            lloc[r] += __builtin_exp2f(v - M2);   // exp2(-1e30) == 0
          }
        }
      }
#pragma unroll
      for (int off = 1; off < 64; off <<= 1)
        wmax = fmaxf(wmax, __shfl_xor(wmax, off));
      if (lane == 0) sBM[wid][kb] = wmax;
    }
    __syncthreads();
  }

  // merge l across the 16 k-residue lanes (bits 0-3); build log2-space gate
  float lrow[4], lgate2[4];
#pragma unroll
  for (int r = 0; r < 4; ++r) {
    float l = lloc[r];
#pragma unroll
    for (int off = 1; off < 16; off <<= 1) l += __shfl_xor(l, off);
    lrow[r] = l;
    lgate2[r] = __log2f(thr * l) + M2;           // keep iff s2 >= lgate2
  }
  float lgmin = fminf(fminf(lgate2[0], lgate2[1]), fminf(lgate2[2], lgate2[3]));
  lgmin = fminf(lgmin, __shfl_xor(lgmin, 16));
  lgmin = fminf(lgmin, __shfl_xor(lgmin, 32));

  // ---- PASS B: QK only on live blocks, gate, PV ----
  f32x4 yacc[8];
#pragma unroll
  for (int n = 0; n < 8; ++n) yacc[n] = f32x4{0.f, 0.f, 0.f, 0.f};

  stageK(0, 0);
  stageV(0, 0);
  __syncthreads();
  for (int kb = 0; kb < nkb; ++kb) {
    int buf = kb & 1;
    if (kb + 1 < nkb) { stageK(buf ^ 1, kb + 1); stageV(buf ^ 1, kb + 1); }
    if (kb * KT <= tq_lo + 15 && sBM[wid][kb] >= lgmin) {
      f32x4 s[2];
      qk(buf, s);
      bool anyk = false;
      float pv[2][4];
      bool full = (kb * KT + KT - 1) <= tq_lo;
#pragma unroll
      for (int nf = 0; nf < 2; ++nf) {
        int tk = kb * KT + nf * 16 + ln15;
#pragma unroll
        for (int r = 0; r < 4; ++r) {
          int tq = tq_lo + ro4 + r;
          float v = s[nf][r] * cs2;
          bool keep = (full || tk <= tq) && (v >= lgate2[r]);
          float p = 0.f;
          if (keep) { p = __builtin_exp2f(v - M2); anyk = true; }
          pv[nf][r] = p;
        }
      }
      if (__any(anyk)) {
#pragma unroll
        for (int nf = 0; nf < 2; ++nf)
#pragma unroll
          for (int r = 0; r < 4; ++r)
            sP[wid][(ro4 + r) * 40 + nf * 16 + ln15] = f2bf(pv[nf][r]);
        __builtin_amdgcn_s_setprio(1);
        bf16x8 pa = *(const bf16x8*)&sP[wid][ln15 * 40 + (lane >> 4) * 8];
#pragma unroll
        for (int nf2 = 0; nf2 < 8; ++nf2) {
          int vrow = nf2 * 16 + ln15;
          int vboff = j16 ^ (((vrow ^ (vrow >> 2)) & 3) << 4);
          bf16x8 vb = *(const bf16x8*)((const char*)sV[buf] + vrow * 64 + vboff);
          yacc[nf2] = __builtin_amdgcn_mfma_f32_16x16x32_bf16(pa, vb, yacc[nf2], 0, 0, 0);
        }
        __builtin_amdgcn_s_setprio(0);
      }
    }
    __syncthreads();
  }

  // epilogue: y (b,t,h,d) bf16
#pragma unroll
  for (int r = 0; r < 4; ++r) {
    int tq = t0 + wid * 16 + ro4 + r;
    float invl = 1.f / lrow[r];
    size_t base = ((size_t)(b * Tdim + tq)) * Cdim + h * 128;
#pragma unroll
    for (int nf2 = 0; nf2 < 8; ++nf2)
      y[base + nf2 * 16 + ln15] = f2bf(yacc[nf2][r] * invl);
  }
}

extern "C" void kernel_launch(void* const* d_in, const int* in_sizes, int n_in,
                              void* d_out, int out_size, void* d_ws, size_t ws_size,
                              hipStream_t stream)
{
  (void)in_sizes; (void)n_in; (void)out_size; (void)ws_size;
  const float* x    = (const float*)d_in[0];
  const float* cosT = (const float*)d_in[1];
  const float* sinT = (const float*)d_in[2];
  const float* Wq   = (const float*)d_in[3];
  const float* Wk   = (const float*)d_in[4];
  const float* Wv   = (const float*)d_in[5];
  const float* Wo   = (const float*)d_in[6];
  const float* gate = (const float*)d_in[7];
  float* out = (float*)d_out;

  char* ws = (char*)d_ws;
  size_t off = 0;
  auto alloc = [&](size_t bytes) -> char* {
    char* p = ws + off; off += (bytes + 255) & ~(size_t)255; return p;
  };
  const size_t NX = (size_t)Bdim * Tdim * Cdim;    // 8388608
  const size_t NK = (size_t)Bdim * Tdim * KVdim;   // 2097152

  unsigned short* xhi   = (unsigned short*)alloc(NX * 2);
  unsigned short* xlo   = (unsigned short*)alloc(NX * 2);
  unsigned short* WqThi = (unsigned short*)alloc((size_t)Cdim * Cdim * 2);
  unsigned short* WqTlo = (unsigned short*)alloc((size_t)Cdim * Cdim * 2);
  unsigned short* WkThi = (unsigned short*)alloc((size_t)Cdim * KVdim * 2);
  unsigned short* WkTlo = (unsigned short*)alloc((size_t)Cdim * KVdim * 2);
  unsigned short* WvThi = (unsigned short*)alloc((size_t)Cdim * KVdim * 2);
  unsigned short* WoThi = (unsigned short*)alloc((size_t)Cdim * Cdim * 2);
  unsigned short* qhi   = (unsigned short*)alloc(NX * 2);
  unsigned short* qlo   = (unsigned short*)alloc(NX * 2);
  unsigned short* khi   = (unsigned short*)alloc(NK * 2);
  unsigned short* klo   = (unsigned short*)alloc(NK * 2);
  unsigned short* vun   = (unsigned short*)alloc(NK * 2);
  unsigned short* vtr   = (unsigned short*)alloc(NK * 2);
  unsigned short* yb    = (unsigned short*)alloc(NX * 2);

  dim3 tb(32, 8);
  split_x_kernel<<<2048, 256, 0, stream>>>(x, xhi, xlo, (int)NX);
  transpose_split_kernel<<<dim3(64, 64), tb, 0, stream>>>(Wq, WqThi, WqTlo, Cdim, Cdim);
  transpose_split_kernel<<<dim3(64, 16), tb, 0, stream>>>(Wk, WkThi, WkTlo, Cdim, KVdim);
  transpose_split_kernel<<<dim3(64, 16), tb, 0, stream>>>(Wv, WvThi, nullptr, Cdim, KVdim);
  transpose_split_kernel<<<dim3(64, 64), tb, 0, stream>>>(Wo, WoThi, nullptr, Cdim, Cdim);

  // q, k (split-3, rope+split fused) and v (1-term) in one dispatch
  qkv_gemm_kernel<<<dim3(32, 24), 256, 0, stream>>>(
      xhi, xlo, WqThi, WqTlo, WkThi, WkTlo, WvThi,
      cosT, sinT, qhi, qlo, khi, klo, vun);
  transpose_v_bf16_kernel<<<dim3(8, 64, 4), tb, 0, stream>>>(vun, vtr);

  attn_kernel<<<dim3(16, 32), 512, 0, stream>>>(qhi, qlo, khi, klo, vtr, gate, yb);

  gemm_wo_kernel<<<dim3(32, 16), 256, 0, stream>>>(yb, WoThi, out);
}